// Round 2
// baseline (14436.324 us; speedup 1.0000x reference)
//
#include <hip/hip_runtime.h>
#include <math.h>

typedef float vf4 __attribute__((ext_vector_type(4)));

#define SEQ   2048
#define DM    1024
#define NH    16
#define DKH   64
// log2(10000)
#define LOG2_THETA 13.287712379549449f
#define INV_2PI    0.15915494309189535f

// ---------------------------------------------------------------------------
// Projection GEMM: C[m,n] = sum_k A[m,k] * W[n,k]   (A row-major MxK, W row-major NxK)
// 128x128 tile, BK=32, 256 threads, 8x8 per thread, register-prefetch staging
// (T14: issue next K-step's global loads right after the stage barrier; write
// them to LDS at the next iteration -> HBM latency hides under compute).
// Interleaved ownership (r = tr+16i, c = tc+16j) + pad 36 keeps every
// ds_read_b128 broadcast or 2-way (free). RoPE fused in epilogue with raw
// v_sin/v_cos (no libm call -> no stack frame -> no accumulator demotion).
// ---------------------------------------------------------------------------
__global__ __launch_bounds__(256, 2) void proj_kernel(
    const float* __restrict__ A,
    const float* __restrict__ W0, const float* __restrict__ W1, const float* __restrict__ W2,
    float* __restrict__ C0, float* __restrict__ C1, float* __restrict__ C2,
    const int* __restrict__ tokpos,
    int M, int N, int K, int ropeMask)
{
    const int z = blockIdx.z;
    const float* __restrict__ W = (z == 0) ? W0 : ((z == 1) ? W1 : W2);
    float* __restrict__ C       = (z == 0) ? C0 : ((z == 1) ? C1 : C2);
    const bool do_rope = (ropeMask >> z) & 1;

    __shared__ float As[128][36];   // 144B row stride: reads are broadcast / 2-way
    __shared__ float Ws[128][36];

    const int t  = threadIdx.x;
    const int tr = t >> 4;          // 0..15
    const int tc = t & 15;          // 0..15
    const int brow = blockIdx.x * 128;
    const int bcol = blockIdx.y * 128;

    // staging: 128x32 tile = 1024 float4, 4 per thread
    const int lrow = t >> 3;        // 0..31
    const int lc4  = (t & 7) << 2;  // 0..28

    float acc[8][8];
    #pragma unroll
    for (int i = 0; i < 8; ++i)
        #pragma unroll
        for (int j = 0; j < 8; ++j) acc[i][j] = 0.f;

    // prologue: prefetch K-step 0 into registers
    vf4 aprf[4], wprf[4];
    #pragma unroll
    for (int i = 0; i < 4; ++i) {
        const int row = lrow + 32 * i;
        aprf[i] = *(const vf4*)(A + (size_t)(brow + row) * K + lc4);
        wprf[i] = *(const vf4*)(W + (size_t)(bcol + row) * K + lc4);
    }

    for (int k0 = 0; k0 < K; k0 += 32) {
        __syncthreads();            // previous compute done reading LDS
        #pragma unroll
        for (int i = 0; i < 4; ++i) {
            const int row = lrow + 32 * i;
            *(vf4*)(&As[row][lc4]) = aprf[i];
            *(vf4*)(&Ws[row][lc4]) = wprf[i];
        }
        __syncthreads();

        if (k0 + 32 < K) {          // issue next-step loads NOW; consumed next iter
            #pragma unroll
            for (int i = 0; i < 4; ++i) {
                const int row = lrow + 32 * i;
                aprf[i] = *(const vf4*)(A + (size_t)(brow + row) * K + (k0 + 32) + lc4);
                wprf[i] = *(const vf4*)(W + (size_t)(bcol + row) * K + (k0 + 32) + lc4);
            }
        }

        #pragma unroll
        for (int kk = 0; kk < 32; kk += 4) {
            vf4 a[8], b[8];
            #pragma unroll
            for (int i = 0; i < 8; ++i) a[i] = *(const vf4*)(&As[tr + 16 * i][kk]);
            #pragma unroll
            for (int j = 0; j < 8; ++j) b[j] = *(const vf4*)(&Ws[tc + 16 * j][kk]);
            #pragma unroll
            for (int i = 0; i < 8; ++i)
                #pragma unroll
                for (int j = 0; j < 8; ++j)
                    acc[i][j] += a[i].x * b[j].x + a[i].y * b[j].y
                               + a[i].z * b[j].z + a[i].w * b[j].w;
        }
    }

    if (do_rope) {
        // col = bcol + tc + 16j ; head-local pair index f = ((col & 63) >> 1)
        // even col: r1 = x1*cos - x2*sin ; odd col: r2 = x1*sin + x2*cos
        // pair partner lives in lane^1 (same rows, same j).
        float pos[8];
        #pragma unroll
        for (int i = 0; i < 8; ++i)
            pos[i] = (float)tokpos[(brow + tr + 16 * i) & (SEQ - 1)];
        #pragma unroll
        for (int j = 0; j < 8; ++j) {
            const int   col = tc + 16 * j;                  // bcol is a multiple of 64
            const float f   = (float)((col & 63) >> 1);
            const float inv = exp2f(f * (-LOG2_THETA / 32.0f));  // theta^(-2f/64)
            #pragma unroll
            for (int i = 0; i < 8; ++i) {
                // sin/cos via hardware op: input in revolutions, explicit fract
                float rev = pos[i] * inv * INV_2PI;
                rev -= floorf(rev);
                const float sv = __builtin_amdgcn_sinf(rev);
                const float cv = __builtin_amdgcn_cosf(rev);
                const float self  = acc[i][j];
                const float other = __shfl_xor(self, 1);
                acc[i][j] = (tc & 1) ? fmaf(other, sv, self * cv)    // odd:  x1*sin + x2*cos
                                     : fmaf(-other, sv, self * cv);  // even: x1*cos - x2*sin
            }
        }
    }

    #pragma unroll
    for (int i = 0; i < 8; ++i) {
        float* crow = C + (size_t)(brow + tr + 16 * i) * N + bcol;
        #pragma unroll
        for (int j = 0; j < 8; ++j)
            crow[tc + 16 * j] = acc[i][j];
    }
}

// ---------------------------------------------------------------------------
// Causal flash attention, fp32. One block per (b,h,q-tile of 64 rows).
// 256 threads as 16x16; scores: rows tr+16i, cols tc+16j (interleaved,
// conflict-free); O accum: rows tr+16i, dims 4*tc+j (contiguous float4 stores).
// Ks buffer reused for P (keeps static LDS at 52KB). K/V for the NEXT k-tile
// are prefetched into registers while the current tile computes (T14).
// ---------------------------------------------------------------------------
__global__ __launch_bounds__(256, 2) void attn_kernel(
    const float* __restrict__ q, const float* __restrict__ k,
    const float* __restrict__ v, float* __restrict__ o)
{
    __shared__ float Qs[64][68];
    __shared__ float Ks[64][68];   // scores' K operand, then P
    __shared__ float Vs[64][68];

    const int bh = blockIdx.y;
    const int b  = bh >> 4;          // / NH
    const int h  = bh & (NH - 1);
    const int qi = (int)gridDim.x - 1 - (int)blockIdx.x;   // heavy tiles dispatch first

    const int t  = threadIdx.x;
    const int tr = t >> 4;
    const int tc = t & 15;

    const size_t base = (size_t)b * SEQ * DM + (size_t)h * DKH;

    // staging: 64 rows x 16 float4 per row, 4 float4 per thread, fully coalesced
    const int lrow = t >> 4;
    const int lc4  = (t & 15) << 2;

    #pragma unroll
    for (int i = 0; i < 4; ++i) {
        const int row = lrow + 16 * i;
        vf4 qv = *(const vf4*)(q + base + (size_t)(qi * 64 + row) * DM + lc4);
        *(vf4*)(&Qs[row][lc4]) = qv * 0.125f;   // 1/sqrt(64) folded into Q
    }

    // prologue: prefetch k-tile 0 into registers
    vf4 kreg[4], vreg[4];
    #pragma unroll
    for (int i = 0; i < 4; ++i) {
        const int row = lrow + 16 * i;
        kreg[i] = *(const vf4*)(k + base + (size_t)row * DM + lc4);
        vreg[i] = *(const vf4*)(v + base + (size_t)row * DM + lc4);
    }

    float oacc[4][4];
    float m_run[4], l_run[4];
    #pragma unroll
    for (int i = 0; i < 4; ++i) {
        m_run[i] = -INFINITY; l_run[i] = 0.f;
        #pragma unroll
        for (int j = 0; j < 4; ++j) oacc[i][j] = 0.f;
    }

    for (int kt = 0; kt <= qi; ++kt) {
        __syncthreads();                       // prev iter done with Ks(P)/Vs; Qs visible
        #pragma unroll
        for (int i = 0; i < 4; ++i) {
            const int row = lrow + 16 * i;
            *(vf4*)(&Ks[row][lc4]) = kreg[i];
            *(vf4*)(&Vs[row][lc4]) = vreg[i];
        }
        __syncthreads();

        if (kt < qi) {                         // prefetch next k-tile into registers
            #pragma unroll
            for (int i = 0; i < 4; ++i) {
                const int row = lrow + 16 * i;
                kreg[i] = *(const vf4*)(k + base + (size_t)((kt + 1) * 64 + row) * DM + lc4);
                vreg[i] = *(const vf4*)(v + base + (size_t)((kt + 1) * 64 + row) * DM + lc4);
            }
        }

        // ---- S = (Q/8) K^T ----
        float sacc[4][4];
        #pragma unroll
        for (int i = 0; i < 4; ++i)
            #pragma unroll
            for (int j = 0; j < 4; ++j) sacc[i][j] = 0.f;

        #pragma unroll
        for (int kk = 0; kk < 64; kk += 4) {
            vf4 a[4], bb[4];
            #pragma unroll
            for (int i = 0; i < 4; ++i) a[i]  = *(const vf4*)(&Qs[tr + 16 * i][kk]);
            #pragma unroll
            for (int j = 0; j < 4; ++j) bb[j] = *(const vf4*)(&Ks[tc + 16 * j][kk]);
            #pragma unroll
            for (int i = 0; i < 4; ++i)
                #pragma unroll
                for (int j = 0; j < 4; ++j)
                    sacc[i][j] += a[i].x * bb[j].x + a[i].y * bb[j].y
                                + a[i].z * bb[j].z + a[i].w * bb[j].w;
        }

        if (kt == qi) {        // diagonal tile: causal mask (local compare is exact)
            #pragma unroll
            for (int i = 0; i < 4; ++i)
                #pragma unroll
                for (int j = 0; j < 4; ++j)
                    if (tc + 16 * j > tr + 16 * i) sacc[i][j] = -INFINITY;
        }

        // ---- online softmax (row lives in 16 consecutive lanes) ----
        #pragma unroll
        for (int i = 0; i < 4; ++i) {
            float mx = fmaxf(fmaxf(sacc[i][0], sacc[i][1]), fmaxf(sacc[i][2], sacc[i][3]));
            mx = fmaxf(mx, __shfl_xor(mx, 1));
            mx = fmaxf(mx, __shfl_xor(mx, 2));
            mx = fmaxf(mx, __shfl_xor(mx, 4));
            mx = fmaxf(mx, __shfl_xor(mx, 8));
            const float mn   = fmaxf(m_run[i], mx);      // finite from first tile on
            const float corr = __expf(m_run[i] - mn);    // exp(-inf)=0 on first tile
            m_run[i] = mn;
            float rs = 0.f;
            #pragma unroll
            for (int j = 0; j < 4; ++j) {
                sacc[i][j] = __expf(sacc[i][j] - mn);    // masked -> 0
                rs += sacc[i][j];
            }
            rs += __shfl_xor(rs, 1);
            rs += __shfl_xor(rs, 2);
            rs += __shfl_xor(rs, 4);
            rs += __shfl_xor(rs, 8);
            l_run[i] = l_run[i] * corr + rs;
            #pragma unroll
            for (int j = 0; j < 4; ++j) oacc[i][j] *= corr;
        }

        __syncthreads();                       // everyone done reading Ks as K
        #pragma unroll
        for (int i = 0; i < 4; ++i)
            #pragma unroll
            for (int j = 0; j < 4; ++j)
                Ks[tr + 16 * i][tc + 16 * j] = sacc[i][j];   // P -> Ks buffer
        __syncthreads();                       // P visible

        // ---- O += P V ----
        #pragma unroll
        for (int cc = 0; cc < 64; cc += 4) {
            vf4 p4[4], v4[4];
            #pragma unroll
            for (int i = 0; i < 4; ++i) p4[i] = *(const vf4*)(&Ks[tr + 16 * i][cc]);
            #pragma unroll
            for (int l = 0; l < 4; ++l) v4[l] = *(const vf4*)(&Vs[cc + l][tc << 2]);
            #pragma unroll
            for (int i = 0; i < 4; ++i)
                #pragma unroll
                for (int j = 0; j < 4; ++j)
                    oacc[i][j] += p4[i][0] * v4[0][j] + p4[i][1] * v4[1][j]
                                + p4[i][2] * v4[2][j] + p4[i][3] * v4[3][j];
        }
    }

    #pragma unroll
    for (int i = 0; i < 4; ++i) {
        const float invl = 1.0f / l_run[i];
        vf4 ov;
        ov.x = oacc[i][0] * invl; ov.y = oacc[i][1] * invl;
        ov.z = oacc[i][2] * invl; ov.w = oacc[i][3] * invl;
        *(vf4*)(o + base + (size_t)(qi * 64 + tr + 16 * i) * DM + (tc << 2)) = ov;
    }
}

// ---------------------------------------------------------------------------
extern "C" void kernel_launch(void* const* d_in, const int* in_sizes, int n_in,
                              void* d_out, int out_size, void* d_ws, size_t ws_size,
                              hipStream_t stream)
{
    const float* x  = (const float*)d_in[0];
    const int*   tp = (const int*)d_in[1];
    const float* Wq = (const float*)d_in[2];
    const float* Wk = (const float*)d_in[3];
    const float* Wv = (const float*)d_in[4];
    const float* Wo = (const float*)d_in[5];
    float* out = (float*)d_out;

    const size_t NELEM = (size_t)2 * SEQ * DM;   // 4,194,304 floats = 16 MB
    float* qb = (float*)d_ws;                    // ws usage: 64 MB total
    float* kb = qb + NELEM;
    float* vb = kb + NELEM;
    float* ob = vb + NELEM;

    const int M = 2 * SEQ;                       // 4096 rows

    // fused Q/K/V projections (z selects W and destination), RoPE on z=0,1
    proj_kernel<<<dim3(M / 128, DM / 128, 3), dim3(256), 0, stream>>>(
        x, Wq, Wk, Wv, qb, kb, vb, tp, M, DM, DM, 0x3);

    // causal flash attention; output lands directly in (B,S,D) layout
    attn_kernel<<<dim3(SEQ / 64, 2 * NH), dim3(256), 0, stream>>>(qb, kb, vb, ob);

    // output projection
    proj_kernel<<<dim3(M / 128, DM / 128, 1), dim3(256), 0, stream>>>(
        ob, Wo, Wo, Wo, out, out, out, tp, M, DM, DM, 0x0);
}

// Round 3
// 11399.815 us; speedup vs baseline: 1.2664x; 1.2664x over previous
//
#include <hip/hip_runtime.h>
#include <math.h>

typedef float vf4 __attribute__((ext_vector_type(4)));

#define SEQ   2048
#define DM    1024
#define NH    16
#define DKH   64
// log2(10000)
#define LOG2_THETA 13.287712379549449f
#define INV_2PI    0.15915494309189535f

// ---------------------------------------------------------------------------
// Projection GEMM: C[m,n] = sum_k A[m,k] * W[n,k]   (A row-major MxK, W row-major NxK)
// 128x128 tile, BK=32, 512 threads, 4x8 per thread (32 acc regs -> total live
// ~110 VGPR, fits the 128-VGPR / 4-waves-per-EU tier with NO SPILL; round-1/2
// used 8x8 = 64 acc and spilled ~15GB of scratch per dispatch).
// Register prefetch of the next K-step hides HBM latency under compute.
// Interleaved ownership (r = tr+32i, c = tc+16j) + pad 36: a-reads are 16-lane
// broadcasts, b-reads are 2-way (free, m136). RoPE fused in epilogue with raw
// v_sin/v_cos (input in revolutions, explicit fract range reduction).
// ---------------------------------------------------------------------------
__global__ __launch_bounds__(512, 4) void proj_kernel(
    const float* __restrict__ A,
    const float* __restrict__ W0, const float* __restrict__ W1, const float* __restrict__ W2,
    float* __restrict__ C0, float* __restrict__ C1, float* __restrict__ C2,
    const int* __restrict__ tokpos,
    int M, int N, int K, int ropeMask)
{
    const int z = blockIdx.z;
    const float* __restrict__ W = (z == 0) ? W0 : ((z == 1) ? W1 : W2);
    float* __restrict__ C       = (z == 0) ? C0 : ((z == 1) ? C1 : C2);
    const bool do_rope = (ropeMask >> z) & 1;

    __shared__ float As[128][36];   // 144B row stride
    __shared__ float Ws[128][36];

    const int t  = threadIdx.x;
    const int tr = t >> 4;          // 0..31  (row base; rows tr + 32*i)
    const int tc = t & 15;          // 0..15  (col base; cols tc + 16*j)
    const int brow = blockIdx.x * 128;
    const int bcol = blockIdx.y * 128;

    // staging: 128x32 tile = 1024 float4 per matrix, 2 per thread per matrix.
    // 8 consecutive lanes cover one full 32-float row contiguously (coalesced).
    const int srow = t >> 3;        // 0..63
    const int sc4  = (t & 7) << 2;  // 0,4,...,28

    float acc[4][8];
    #pragma unroll
    for (int i = 0; i < 4; ++i)
        #pragma unroll
        for (int j = 0; j < 8; ++j) acc[i][j] = 0.f;

    // prologue: prefetch K-step 0 into registers (4 vf4 = 16 VGPRs)
    vf4 aprf[2], wprf[2];
    #pragma unroll
    for (int s = 0; s < 2; ++s) {
        const int row = srow + 64 * s;
        aprf[s] = *(const vf4*)(A + (size_t)(brow + row) * K + sc4);
        wprf[s] = *(const vf4*)(W + (size_t)(bcol + row) * K + sc4);
    }

    for (int k0 = 0; k0 < K; k0 += 32) {
        __syncthreads();            // previous compute done reading LDS
        #pragma unroll
        for (int s = 0; s < 2; ++s) {
            const int row = srow + 64 * s;
            *(vf4*)(&As[row][sc4]) = aprf[s];
            *(vf4*)(&Ws[row][sc4]) = wprf[s];
        }
        __syncthreads();

        if (k0 + 32 < K) {          // issue next-step loads now; consumed next iter
            #pragma unroll
            for (int s = 0; s < 2; ++s) {
                const int row = srow + 64 * s;
                aprf[s] = *(const vf4*)(A + (size_t)(brow + row) * K + (k0 + 32) + sc4);
                wprf[s] = *(const vf4*)(W + (size_t)(bcol + row) * K + (k0 + 32) + sc4);
            }
        }

        #pragma unroll
        for (int kk = 0; kk < 32; kk += 4) {
            vf4 a[4], b[8];
            #pragma unroll
            for (int i = 0; i < 4; ++i) a[i] = *(const vf4*)(&As[tr + 32 * i][kk]);
            #pragma unroll
            for (int j = 0; j < 8; ++j) b[j] = *(const vf4*)(&Ws[tc + 16 * j][kk]);
            #pragma unroll
            for (int i = 0; i < 4; ++i)
                #pragma unroll
                for (int j = 0; j < 8; ++j)
                    acc[i][j] += a[i].x * b[j].x + a[i].y * b[j].y
                               + a[i].z * b[j].z + a[i].w * b[j].w;
        }
    }

    if (do_rope) {
        // col = bcol + tc + 16j ; head-local pair index f = ((col & 63) >> 1)
        // even col: r1 = x1*cos - x2*sin ; odd col: r2 = x1*sin + x2*cos
        // pair partner (same rows, same j, col^1) lives in lane^1.
        float pos[4];
        #pragma unroll
        for (int i = 0; i < 4; ++i)
            pos[i] = (float)tokpos[(brow + tr + 32 * i) & (SEQ - 1)];
        #pragma unroll
        for (int j = 0; j < 8; ++j) {
            const int   col = tc + 16 * j;                  // bcol multiple of 64
            const float f   = (float)((col & 63) >> 1);
            const float inv = exp2f(f * (-LOG2_THETA / 32.0f));  // theta^(-2f/64)
            #pragma unroll
            for (int i = 0; i < 4; ++i) {
                float rev = pos[i] * inv * INV_2PI;        // radians -> revolutions
                rev -= floorf(rev);
                const float sv = __builtin_amdgcn_sinf(rev);
                const float cv = __builtin_amdgcn_cosf(rev);
                const float self  = acc[i][j];
                const float other = __shfl_xor(self, 1);
                acc[i][j] = (tc & 1) ? fmaf(other, sv, self * cv)    // odd:  x1*sin + x2*cos
                                     : fmaf(-other, sv, self * cv);  // even: x1*cos - x2*sin
            }
        }
    }

    #pragma unroll
    for (int i = 0; i < 4; ++i) {
        float* crow = C + (size_t)(brow + tr + 32 * i) * N + bcol;
        #pragma unroll
        for (int j = 0; j < 8; ++j)
            crow[tc + 16 * j] = acc[i][j];
    }
}

// ---------------------------------------------------------------------------
// Causal flash attention, fp32 (round-1 structure: no reg prefetch, low
// pressure ~80 VGPR). One block per (b,h,q-tile of 64 rows), 256 threads as
// 16x16. Scores rows tr+16i, cols tc+16j (conflict-free); O accum rows
// tr+16i, dims 4*tc+j (contiguous float4 stores). Ks buffer reused for P.
// ---------------------------------------------------------------------------
__global__ __launch_bounds__(256, 2) void attn_kernel(
    const float* __restrict__ q, const float* __restrict__ k,
    const float* __restrict__ v, float* __restrict__ o)
{
    __shared__ float Qs[64][68];
    __shared__ float Ks[64][68];   // scores' K operand, then P
    __shared__ float Vs[64][68];

    const int bh = blockIdx.y;
    const int b  = bh >> 4;          // / NH
    const int h  = bh & (NH - 1);
    const int qi = (int)gridDim.x - 1 - (int)blockIdx.x;   // heavy tiles first

    const int t  = threadIdx.x;
    const int tr = t >> 4;
    const int tc = t & 15;

    const size_t base = (size_t)b * SEQ * DM + (size_t)h * DKH;

    const int lrow = t >> 4;
    const int lc4  = (t & 15) << 2;

    #pragma unroll
    for (int i = 0; i < 4; ++i) {
        const int row = lrow + 16 * i;
        vf4 qv = *(const vf4*)(q + base + (size_t)(qi * 64 + row) * DM + lc4);
        *(vf4*)(&Qs[row][lc4]) = qv * 0.125f;   // 1/sqrt(64) folded into Q
    }

    float oacc[4][4];
    float m_run[4], l_run[4];
    #pragma unroll
    for (int i = 0; i < 4; ++i) {
        m_run[i] = -INFINITY; l_run[i] = 0.f;
        #pragma unroll
        for (int j = 0; j < 4; ++j) oacc[i][j] = 0.f;
    }

    for (int kt = 0; kt <= qi; ++kt) {
        __syncthreads();                       // prev iter done with Ks(P)/Vs
        #pragma unroll
        for (int i = 0; i < 4; ++i) {
            const int row = lrow + 16 * i;
            *(vf4*)(&Ks[row][lc4]) = *(const vf4*)(k + base + (size_t)(kt * 64 + row) * DM + lc4);
            *(vf4*)(&Vs[row][lc4]) = *(const vf4*)(v + base + (size_t)(kt * 64 + row) * DM + lc4);
        }
        __syncthreads();

        // ---- S = (Q/8) K^T ----
        float sacc[4][4];
        #pragma unroll
        for (int i = 0; i < 4; ++i)
            #pragma unroll
            for (int j = 0; j < 4; ++j) sacc[i][j] = 0.f;

        #pragma unroll
        for (int kk = 0; kk < 64; kk += 4) {
            vf4 a[4], bb[4];
            #pragma unroll
            for (int i = 0; i < 4; ++i) a[i]  = *(const vf4*)(&Qs[tr + 16 * i][kk]);
            #pragma unroll
            for (int j = 0; j < 4; ++j) bb[j] = *(const vf4*)(&Ks[tc + 16 * j][kk]);
            #pragma unroll
            for (int i = 0; i < 4; ++i)
                #pragma unroll
                for (int j = 0; j < 4; ++j)
                    sacc[i][j] += a[i].x * bb[j].x + a[i].y * bb[j].y
                                + a[i].z * bb[j].z + a[i].w * bb[j].w;
        }

        if (kt == qi) {        // diagonal tile: causal mask
            #pragma unroll
            for (int i = 0; i < 4; ++i)
                #pragma unroll
                for (int j = 0; j < 4; ++j)
                    if (tc + 16 * j > tr + 16 * i) sacc[i][j] = -INFINITY;
        }

        // ---- online softmax (row lives in 16 consecutive lanes) ----
        #pragma unroll
        for (int i = 0; i < 4; ++i) {
            float mx = fmaxf(fmaxf(sacc[i][0], sacc[i][1]), fmaxf(sacc[i][2], sacc[i][3]));
            mx = fmaxf(mx, __shfl_xor(mx, 1));
            mx = fmaxf(mx, __shfl_xor(mx, 2));
            mx = fmaxf(mx, __shfl_xor(mx, 4));
            mx = fmaxf(mx, __shfl_xor(mx, 8));
            const float mn   = fmaxf(m_run[i], mx);
            const float corr = __expf(m_run[i] - mn);    // exp(-inf)=0 on first tile
            m_run[i] = mn;
            float rs = 0.f;
            #pragma unroll
            for (int j = 0; j < 4; ++j) {
                sacc[i][j] = __expf(sacc[i][j] - mn);    // masked -> 0
                rs += sacc[i][j];
            }
            rs += __shfl_xor(rs, 1);
            rs += __shfl_xor(rs, 2);
            rs += __shfl_xor(rs, 4);
            rs += __shfl_xor(rs, 8);
            l_run[i] = l_run[i] * corr + rs;
            #pragma unroll
            for (int j = 0; j < 4; ++j) oacc[i][j] *= corr;
        }

        __syncthreads();                       // everyone done reading Ks as K
        #pragma unroll
        for (int i = 0; i < 4; ++i)
            #pragma unroll
            for (int j = 0; j < 4; ++j)
                Ks[tr + 16 * i][tc + 16 * j] = sacc[i][j];   // P -> Ks buffer
        __syncthreads();                       // P visible

        // ---- O += P V ----
        #pragma unroll
        for (int cc = 0; cc < 64; cc += 4) {
            vf4 p4[4], v4[4];
            #pragma unroll
            for (int i = 0; i < 4; ++i) p4[i] = *(const vf4*)(&Ks[tr + 16 * i][cc]);
            #pragma unroll
            for (int l = 0; l < 4; ++l) v4[l] = *(const vf4*)(&Vs[cc + l][tc << 2]);
            #pragma unroll
            for (int i = 0; i < 4; ++i)
                #pragma unroll
                for (int j = 0; j < 4; ++j)
                    oacc[i][j] += p4[i][0] * v4[0][j] + p4[i][1] * v4[1][j]
                                + p4[i][2] * v4[2][j] + p4[i][3] * v4[3][j];
        }
    }

    #pragma unroll
    for (int i = 0; i < 4; ++i) {
        const float invl = 1.0f / l_run[i];
        vf4 ov;
        ov.x = oacc[i][0] * invl; ov.y = oacc[i][1] * invl;
        ov.z = oacc[i][2] * invl; ov.w = oacc[i][3] * invl;
        *(vf4*)(o + base + (size_t)(qi * 64 + tr + 16 * i) * DM + (tc << 2)) = ov;
    }
}

// ---------------------------------------------------------------------------
extern "C" void kernel_launch(void* const* d_in, const int* in_sizes, int n_in,
                              void* d_out, int out_size, void* d_ws, size_t ws_size,
                              hipStream_t stream)
{
    const float* x  = (const float*)d_in[0];
    const int*   tp = (const int*)d_in[1];
    const float* Wq = (const float*)d_in[2];
    const float* Wk = (const float*)d_in[3];
    const float* Wv = (const float*)d_in[4];
    const float* Wo = (const float*)d_in[5];
    float* out = (float*)d_out;

    const size_t NELEM = (size_t)2 * SEQ * DM;   // 4,194,304 floats = 16 MB
    float* qb = (float*)d_ws;                    // ws usage: 64 MB total
    float* kb = qb + NELEM;
    float* vb = kb + NELEM;
    float* ob = vb + NELEM;

    const int M = 2 * SEQ;                       // 4096 rows

    // fused Q/K/V projections (z selects W and destination), RoPE on z=0,1
    proj_kernel<<<dim3(M / 128, DM / 128, 3), dim3(512), 0, stream>>>(
        x, Wq, Wk, Wv, qb, kb, vb, tp, M, DM, DM, 0x3);

    // causal flash attention; output lands directly in (B,S,D) layout
    attn_kernel<<<dim3(SEQ / 64, 2 * NH), dim3(256), 0, stream>>>(qb, kb, vb, ob);

    // output projection
    proj_kernel<<<dim3(M / 128, DM / 128, 1), dim3(512), 0, stream>>>(
        ob, Wo, Wo, Wo, out, out, out, tp, M, DM, DM, 0x0);
}

// Round 4
// 2443.446 us; speedup vs baseline: 5.9082x; 4.6655x over previous
//
#include <hip/hip_runtime.h>
#include <math.h>

typedef float vf4 __attribute__((ext_vector_type(4)));

#define SEQ   2048
#define DM    1024
#define NH    16
#define DKH   64
// log2(10000)
#define LOG2_THETA 13.287712379549449f
#define INV_2PI    0.15915494309189535f

// ---------------------------------------------------------------------------
// Projection GEMM: C[m,n] = sum_k A[m,k] * W[n,k]  (A MxK row-major, W NxK row-major)
// 128x128 tile, BK=32, 512 threads, 4x8 per thread.
// FULLY SCALARIZED: no local arrays anywhere -> nothing can be demoted to
// scratch (rounds 1-3 all had the accumulator in scratch: 13-15GB of spill
// traffic per dispatch, VALUBusy <8%, dispatch BW-bound at ~3.2TB/s).
// Interleaved ownership (rows tr+32i, cols tc+16j), pad 36 -> LDS reads are
// 16-lane broadcast (a) / 2-way (b) = free; staging measured 0 conflicts.
// Register prefetch of next K-step hides HBM latency under compute.
// ---------------------------------------------------------------------------

#define DOT1(I, J, AV, BV) \
    acc##I##J = fmaf(AV.x, BV.x, fmaf(AV.y, BV.y, fmaf(AV.z, BV.z, fmaf(AV.w, BV.w, acc##I##J))))

#define DOTROW(I, AV) \
    DOT1(I, 0, AV, b0); DOT1(I, 1, AV, b1); DOT1(I, 2, AV, b2); DOT1(I, 3, AV, b3); \
    DOT1(I, 4, AV, b4); DOT1(I, 5, AV, b5); DOT1(I, 6, AV, b6); DOT1(I, 7, AV, b7)

#define ROPE1(I, J, INV) { \
    float rev = pos##I * (INV) * INV_2PI; \
    rev -= floorf(rev); \
    const float sv = __builtin_amdgcn_sinf(rev); \
    const float cv = __builtin_amdgcn_cosf(rev); \
    const float self  = acc##I##J; \
    const float other = __shfl_xor(self, 1); \
    acc##I##J = odd ? fmaf(other, sv, self * cv) : fmaf(-other, sv, self * cv); }

#define ROPEJ(J) { \
    const float fj  = (float)(((tc + 16 * (J)) & 63) >> 1); \
    const float inv = exp2f(fj * (-LOG2_THETA / 32.0f)); \
    ROPE1(0, J, inv) ROPE1(1, J, inv) ROPE1(2, J, inv) ROPE1(3, J, inv) }

#define CWRITE(I) { \
    float* crow = C + (size_t)(brow + tr + 32 * (I)) * N + bcol + tc; \
    crow[0]   = acc##I##0; crow[16]  = acc##I##1; crow[32]  = acc##I##2; crow[48]  = acc##I##3; \
    crow[64]  = acc##I##4; crow[80]  = acc##I##5; crow[96]  = acc##I##6; crow[112] = acc##I##7; }

__global__ __launch_bounds__(512, 2) void proj_kernel(
    const float* __restrict__ A,
    const float* __restrict__ W0, const float* __restrict__ W1, const float* __restrict__ W2,
    float* __restrict__ C0, float* __restrict__ C1, float* __restrict__ C2,
    const int* __restrict__ tokpos,
    int M, int N, int K, int ropeMask)
{
    const int z = blockIdx.z;
    const float* __restrict__ W = (z == 0) ? W0 : ((z == 1) ? W1 : W2);
    float* __restrict__ C       = (z == 0) ? C0 : ((z == 1) ? C1 : C2);
    const bool do_rope = (ropeMask >> z) & 1;

    __shared__ float As[128][36];   // 144B row stride
    __shared__ float Ws[128][36];

    const int t  = threadIdx.x;
    const int tr = t >> 4;          // 0..31 (rows tr + 32*i)
    const int tc = t & 15;          // 0..15 (cols tc + 16*j)
    const int brow = blockIdx.x * 128;
    const int bcol = blockIdx.y * 128;

    // staging: 8 consecutive lanes cover one 32-float row contiguously
    const int srow = t >> 3;        // 0..63
    const int sc4  = (t & 7) << 2;  // 0,4,...,28

    const float* Arow0 = A + (size_t)(brow + srow) * K + sc4;
    const float* Arow1 = A + (size_t)(brow + srow + 64) * K + sc4;
    const float* Wrow0 = W + (size_t)(bcol + srow) * K + sc4;
    const float* Wrow1 = W + (size_t)(bcol + srow + 64) * K + sc4;

    float acc00 = 0.f, acc01 = 0.f, acc02 = 0.f, acc03 = 0.f;
    float acc04 = 0.f, acc05 = 0.f, acc06 = 0.f, acc07 = 0.f;
    float acc10 = 0.f, acc11 = 0.f, acc12 = 0.f, acc13 = 0.f;
    float acc14 = 0.f, acc15 = 0.f, acc16 = 0.f, acc17 = 0.f;
    float acc20 = 0.f, acc21 = 0.f, acc22 = 0.f, acc23 = 0.f;
    float acc24 = 0.f, acc25 = 0.f, acc26 = 0.f, acc27 = 0.f;
    float acc30 = 0.f, acc31 = 0.f, acc32 = 0.f, acc33 = 0.f;
    float acc34 = 0.f, acc35 = 0.f, acc36 = 0.f, acc37 = 0.f;

    // prologue prefetch of K-step 0 (named regs, no arrays)
    vf4 aprf0 = *(const vf4*)(Arow0);
    vf4 aprf1 = *(const vf4*)(Arow1);
    vf4 wprf0 = *(const vf4*)(Wrow0);
    vf4 wprf1 = *(const vf4*)(Wrow1);

    for (int k0 = 0; k0 < K; k0 += 32) {
        __syncthreads();            // previous compute done reading LDS
        *(vf4*)(&As[srow     ][sc4]) = aprf0;
        *(vf4*)(&As[srow + 64][sc4]) = aprf1;
        *(vf4*)(&Ws[srow     ][sc4]) = wprf0;
        *(vf4*)(&Ws[srow + 64][sc4]) = wprf1;
        __syncthreads();

        if (k0 + 32 < K) {          // issue next-step loads now; consumed next iter
            aprf0 = *(const vf4*)(Arow0 + k0 + 32);
            aprf1 = *(const vf4*)(Arow1 + k0 + 32);
            wprf0 = *(const vf4*)(Wrow0 + k0 + 32);
            wprf1 = *(const vf4*)(Wrow1 + k0 + 32);
        }

        #pragma unroll
        for (int kk = 0; kk < 32; kk += 4) {
            const vf4 a0 = *(const vf4*)(&As[tr     ][kk]);
            const vf4 a1 = *(const vf4*)(&As[tr + 32][kk]);
            const vf4 a2 = *(const vf4*)(&As[tr + 64][kk]);
            const vf4 a3 = *(const vf4*)(&As[tr + 96][kk]);
            const vf4 b0 = *(const vf4*)(&Ws[tc      ][kk]);
            const vf4 b1 = *(const vf4*)(&Ws[tc + 16 ][kk]);
            const vf4 b2 = *(const vf4*)(&Ws[tc + 32 ][kk]);
            const vf4 b3 = *(const vf4*)(&Ws[tc + 48 ][kk]);
            const vf4 b4 = *(const vf4*)(&Ws[tc + 64 ][kk]);
            const vf4 b5 = *(const vf4*)(&Ws[tc + 80 ][kk]);
            const vf4 b6 = *(const vf4*)(&Ws[tc + 96 ][kk]);
            const vf4 b7 = *(const vf4*)(&Ws[tc + 112][kk]);
            DOTROW(0, a0);
            DOTROW(1, a1);
            DOTROW(2, a2);
            DOTROW(3, a3);
        }
    }

    if (do_rope) {
        // col = bcol + tc + 16j ; head-local pair f = ((col&63)>>1); partner in lane^1
        const float pos0 = (float)tokpos[(brow + tr     ) & (SEQ - 1)];
        const float pos1 = (float)tokpos[(brow + tr + 32) & (SEQ - 1)];
        const float pos2 = (float)tokpos[(brow + tr + 64) & (SEQ - 1)];
        const float pos3 = (float)tokpos[(brow + tr + 96) & (SEQ - 1)];
        const bool odd = (tc & 1);
        ROPEJ(0) ROPEJ(1) ROPEJ(2) ROPEJ(3)
        ROPEJ(4) ROPEJ(5) ROPEJ(6) ROPEJ(7)
    }

    CWRITE(0) CWRITE(1) CWRITE(2) CWRITE(3)
}

// ---------------------------------------------------------------------------
// Causal flash attention, fp32, FULLY SCALARIZED (same anti-scratch treatment).
// One block per (b,h,64-row q-tile), 256 threads as 16x16.
// Scores rows tr+16i, cols tc+16j; O accum rows tr+16i, dims 4*tc+j.
// Ks buffer reused for P between the two matmuls.
// ---------------------------------------------------------------------------

#define QK_ROW(I) { \
    const vf4 a = *(const vf4*)(&Qs[tr + 16 * (I)][kk]); \
    s##I##0 = fmaf(a.x, b0.x, fmaf(a.y, b0.y, fmaf(a.z, b0.z, fmaf(a.w, b0.w, s##I##0)))); \
    s##I##1 = fmaf(a.x, b1.x, fmaf(a.y, b1.y, fmaf(a.z, b1.z, fmaf(a.w, b1.w, s##I##1)))); \
    s##I##2 = fmaf(a.x, b2.x, fmaf(a.y, b2.y, fmaf(a.z, b2.z, fmaf(a.w, b2.w, s##I##2)))); \
    s##I##3 = fmaf(a.x, b3.x, fmaf(a.y, b3.y, fmaf(a.z, b3.z, fmaf(a.w, b3.w, s##I##3)))); }

#define MASK_ROW(I) { \
    if (tc      > tr + 16 * (I)) s##I##0 = -INFINITY; \
    if (tc + 16 > tr + 16 * (I)) s##I##1 = -INFINITY; \
    if (tc + 32 > tr + 16 * (I)) s##I##2 = -INFINITY; \
    if (tc + 48 > tr + 16 * (I)) s##I##3 = -INFINITY; }

#define SOFTMAX_ROW(I) { \
    float mx = fmaxf(fmaxf(s##I##0, s##I##1), fmaxf(s##I##2, s##I##3)); \
    mx = fmaxf(mx, __shfl_xor(mx, 1)); \
    mx = fmaxf(mx, __shfl_xor(mx, 2)); \
    mx = fmaxf(mx, __shfl_xor(mx, 4)); \
    mx = fmaxf(mx, __shfl_xor(mx, 8)); \
    const float mn   = fmaxf(m##I, mx); \
    const float corr = __expf(m##I - mn); \
    m##I = mn; \
    s##I##0 = __expf(s##I##0 - mn); \
    s##I##1 = __expf(s##I##1 - mn); \
    s##I##2 = __expf(s##I##2 - mn); \
    s##I##3 = __expf(s##I##3 - mn); \
    float rs = (s##I##0 + s##I##1) + (s##I##2 + s##I##3); \
    rs += __shfl_xor(rs, 1); \
    rs += __shfl_xor(rs, 2); \
    rs += __shfl_xor(rs, 4); \
    rs += __shfl_xor(rs, 8); \
    l##I = fmaf(l##I, corr, rs); \
    o##I##0 *= corr; o##I##1 *= corr; o##I##2 *= corr; o##I##3 *= corr; }

#define PSTORE_ROW(I) { \
    float* prow = &Ks[tr + 16 * (I)][tc]; \
    prow[0]  = s##I##0; prow[16] = s##I##1; prow[32] = s##I##2; prow[48] = s##I##3; }

#define PV_ROW(I) { \
    const vf4 p = *(const vf4*)(&Ks[tr + 16 * (I)][cc]); \
    o##I##0 = fmaf(p.x, v0.x, fmaf(p.y, v1.x, fmaf(p.z, v2.x, fmaf(p.w, v3.x, o##I##0)))); \
    o##I##1 = fmaf(p.x, v0.y, fmaf(p.y, v1.y, fmaf(p.z, v2.y, fmaf(p.w, v3.y, o##I##1)))); \
    o##I##2 = fmaf(p.x, v0.z, fmaf(p.y, v1.z, fmaf(p.z, v2.z, fmaf(p.w, v3.z, o##I##2)))); \
    o##I##3 = fmaf(p.x, v0.w, fmaf(p.y, v1.w, fmaf(p.z, v2.w, fmaf(p.w, v3.w, o##I##3)))); }

#define OUT_ROW(I) { \
    const float invl = 1.0f / l##I; \
    vf4 ov; \
    ov.x = o##I##0 * invl; ov.y = o##I##1 * invl; \
    ov.z = o##I##2 * invl; ov.w = o##I##3 * invl; \
    *(vf4*)(o + base + (size_t)(qi * 64 + tr + 16 * (I)) * DM + (tc << 2)) = ov; }

__global__ __launch_bounds__(256, 2) void attn_kernel(
    const float* __restrict__ q, const float* __restrict__ k,
    const float* __restrict__ v, float* __restrict__ o)
{
    __shared__ float Qs[64][68];
    __shared__ float Ks[64][68];   // K operand, then P
    __shared__ float Vs[64][68];

    const int bh = blockIdx.y;
    const int b  = bh >> 4;          // / NH
    const int h  = bh & (NH - 1);
    const int qi = (int)gridDim.x - 1 - (int)blockIdx.x;   // heavy tiles first

    const int t  = threadIdx.x;
    const int tr = t >> 4;
    const int tc = t & 15;

    const size_t base = (size_t)b * SEQ * DM + (size_t)h * DKH;

    const int lrow = t >> 4;          // 0..15
    const int lc4  = (t & 15) << 2;   // 0..60

    {
        vf4 q0 = *(const vf4*)(q + base + (size_t)(qi * 64 + lrow     ) * DM + lc4);
        vf4 q1 = *(const vf4*)(q + base + (size_t)(qi * 64 + lrow + 16) * DM + lc4);
        vf4 q2 = *(const vf4*)(q + base + (size_t)(qi * 64 + lrow + 32) * DM + lc4);
        vf4 q3 = *(const vf4*)(q + base + (size_t)(qi * 64 + lrow + 48) * DM + lc4);
        *(vf4*)(&Qs[lrow     ][lc4]) = q0 * 0.125f;   // 1/sqrt(64) folded in
        *(vf4*)(&Qs[lrow + 16][lc4]) = q1 * 0.125f;
        *(vf4*)(&Qs[lrow + 32][lc4]) = q2 * 0.125f;
        *(vf4*)(&Qs[lrow + 48][lc4]) = q3 * 0.125f;
    }

    float o00 = 0.f, o01 = 0.f, o02 = 0.f, o03 = 0.f;
    float o10 = 0.f, o11 = 0.f, o12 = 0.f, o13 = 0.f;
    float o20 = 0.f, o21 = 0.f, o22 = 0.f, o23 = 0.f;
    float o30 = 0.f, o31 = 0.f, o32 = 0.f, o33 = 0.f;
    float m0 = -INFINITY, m1 = -INFINITY, m2 = -INFINITY, m3 = -INFINITY;
    float l0 = 0.f, l1 = 0.f, l2 = 0.f, l3 = 0.f;

    for (int kt = 0; kt <= qi; ++kt) {
        __syncthreads();                       // prev iter done with Ks(P)/Vs
        {
            const float* kp = k + base + (size_t)(kt * 64) * DM;
            const float* vp = v + base + (size_t)(kt * 64) * DM;
            *(vf4*)(&Ks[lrow     ][lc4]) = *(const vf4*)(kp + (size_t)(lrow     ) * DM + lc4);
            *(vf4*)(&Ks[lrow + 16][lc4]) = *(const vf4*)(kp + (size_t)(lrow + 16) * DM + lc4);
            *(vf4*)(&Ks[lrow + 32][lc4]) = *(const vf4*)(kp + (size_t)(lrow + 32) * DM + lc4);
            *(vf4*)(&Ks[lrow + 48][lc4]) = *(const vf4*)(kp + (size_t)(lrow + 48) * DM + lc4);
            *(vf4*)(&Vs[lrow     ][lc4]) = *(const vf4*)(vp + (size_t)(lrow     ) * DM + lc4);
            *(vf4*)(&Vs[lrow + 16][lc4]) = *(const vf4*)(vp + (size_t)(lrow + 16) * DM + lc4);
            *(vf4*)(&Vs[lrow + 32][lc4]) = *(const vf4*)(vp + (size_t)(lrow + 32) * DM + lc4);
            *(vf4*)(&Vs[lrow + 48][lc4]) = *(const vf4*)(vp + (size_t)(lrow + 48) * DM + lc4);
        }
        __syncthreads();

        // ---- S = (Q/8) K^T ----
        float s00 = 0.f, s01 = 0.f, s02 = 0.f, s03 = 0.f;
        float s10 = 0.f, s11 = 0.f, s12 = 0.f, s13 = 0.f;
        float s20 = 0.f, s21 = 0.f, s22 = 0.f, s23 = 0.f;
        float s30 = 0.f, s31 = 0.f, s32 = 0.f, s33 = 0.f;

        #pragma unroll
        for (int kk = 0; kk < 64; kk += 4) {
            const vf4 b0 = *(const vf4*)(&Ks[tc     ][kk]);
            const vf4 b1 = *(const vf4*)(&Ks[tc + 16][kk]);
            const vf4 b2 = *(const vf4*)(&Ks[tc + 32][kk]);
            const vf4 b3 = *(const vf4*)(&Ks[tc + 48][kk]);
            QK_ROW(0) QK_ROW(1) QK_ROW(2) QK_ROW(3)
        }

        if (kt == qi) {       // diagonal tile: causal mask
            MASK_ROW(0) MASK_ROW(1) MASK_ROW(2) MASK_ROW(3)
        }

        // ---- online softmax (row lives in 16 consecutive lanes) ----
        SOFTMAX_ROW(0) SOFTMAX_ROW(1) SOFTMAX_ROW(2) SOFTMAX_ROW(3)

        __syncthreads();                       // all done reading Ks as K
        PSTORE_ROW(0) PSTORE_ROW(1) PSTORE_ROW(2) PSTORE_ROW(3)
        __syncthreads();                       // P visible

        // ---- O += P V ----
        #pragma unroll
        for (int cc = 0; cc < 64; cc += 4) {
            const vf4 v0 = *(const vf4*)(&Vs[cc    ][tc << 2]);
            const vf4 v1 = *(const vf4*)(&Vs[cc + 1][tc << 2]);
            const vf4 v2 = *(const vf4*)(&Vs[cc + 2][tc << 2]);
            const vf4 v3 = *(const vf4*)(&Vs[cc + 3][tc << 2]);
            PV_ROW(0) PV_ROW(1) PV_ROW(2) PV_ROW(3)
        }
    }

    OUT_ROW(0) OUT_ROW(1) OUT_ROW(2) OUT_ROW(3)
}

// ---------------------------------------------------------------------------
extern "C" void kernel_launch(void* const* d_in, const int* in_sizes, int n_in,
                              void* d_out, int out_size, void* d_ws, size_t ws_size,
                              hipStream_t stream)
{
    const float* x  = (const float*)d_in[0];
    const int*   tp = (const int*)d_in[1];
    const float* Wq = (const float*)d_in[2];
    const float* Wk = (const float*)d_in[3];
    const float* Wv = (const float*)d_in[4];
    const float* Wo = (const float*)d_in[5];
    float* out = (float*)d_out;

    const size_t NELEM = (size_t)2 * SEQ * DM;   // 4,194,304 floats = 16 MB
    float* qb = (float*)d_ws;                    // ws usage: 64 MB total
    float* kb = qb + NELEM;
    float* vb = kb + NELEM;
    float* ob = vb + NELEM;

    const int M = 2 * SEQ;                       // 4096 rows

    // fused Q/K/V projections (z selects W and destination), RoPE on z=0,1
    proj_kernel<<<dim3(M / 128, DM / 128, 3), dim3(512), 0, stream>>>(
        x, Wq, Wk, Wv, qb, kb, vb, tp, M, DM, DM, 0x3);

    // causal flash attention; output lands directly in (B,S,D) layout
    attn_kernel<<<dim3(SEQ / 64, 2 * NH), dim3(256), 0, stream>>>(qb, kb, vb, ob);

    // output projection
    proj_kernel<<<dim3(M / 128, DM / 128, 1), dim3(512), 0, stream>>>(
        ob, Wo, Wo, Wo, out, out, out, tp, M, DM, DM, 0x0);
}

// Round 5
// 1178.177 us; speedup vs baseline: 12.2531x; 2.0739x over previous
//
#include <hip/hip_runtime.h>
#include <math.h>

typedef float vf4 __attribute__((ext_vector_type(4)));

#define SEQ   2048
#define DM    1024
#define NH    16
#define DKH   64
// log2(10000)
#define LOG2_THETA 13.287712379549449f
#define INV_2PI    0.15915494309189535f

// ---------------------------------------------------------------------------
// Projection GEMM (unchanged from round 4 — spill-free, ~530us for all 4 GEMMs)
// ---------------------------------------------------------------------------

#define DOT1(I, J, AV, BV) \
    acc##I##J = fmaf(AV.x, BV.x, fmaf(AV.y, BV.y, fmaf(AV.z, BV.z, fmaf(AV.w, BV.w, acc##I##J))))

#define DOTROW(I, AV) \
    DOT1(I, 0, AV, b0); DOT1(I, 1, AV, b1); DOT1(I, 2, AV, b2); DOT1(I, 3, AV, b3); \
    DOT1(I, 4, AV, b4); DOT1(I, 5, AV, b5); DOT1(I, 6, AV, b6); DOT1(I, 7, AV, b7)

#define ROPE1(I, J, INV) { \
    float rev = pos##I * (INV) * INV_2PI; \
    rev -= floorf(rev); \
    const float sv = __builtin_amdgcn_sinf(rev); \
    const float cv = __builtin_amdgcn_cosf(rev); \
    const float self  = acc##I##J; \
    const float other = __shfl_xor(self, 1); \
    acc##I##J = odd ? fmaf(other, sv, self * cv) : fmaf(-other, sv, self * cv); }

#define ROPEJ(J) { \
    const float fj  = (float)(((tc + 16 * (J)) & 63) >> 1); \
    const float inv = exp2f(fj * (-LOG2_THETA / 32.0f)); \
    ROPE1(0, J, inv) ROPE1(1, J, inv) ROPE1(2, J, inv) ROPE1(3, J, inv) }

#define CWRITE(I) { \
    float* crow = C + (size_t)(brow + tr + 32 * (I)) * N + bcol + tc; \
    crow[0]   = acc##I##0; crow[16]  = acc##I##1; crow[32]  = acc##I##2; crow[48]  = acc##I##3; \
    crow[64]  = acc##I##4; crow[80]  = acc##I##5; crow[96]  = acc##I##6; crow[112] = acc##I##7; }

__global__ __launch_bounds__(512, 2) void proj_kernel(
    const float* __restrict__ A,
    const float* __restrict__ W0, const float* __restrict__ W1, const float* __restrict__ W2,
    float* __restrict__ C0, float* __restrict__ C1, float* __restrict__ C2,
    const int* __restrict__ tokpos,
    int M, int N, int K, int ropeMask)
{
    const int z = blockIdx.z;
    const float* __restrict__ W = (z == 0) ? W0 : ((z == 1) ? W1 : W2);
    float* __restrict__ C       = (z == 0) ? C0 : ((z == 1) ? C1 : C2);
    const bool do_rope = (ropeMask >> z) & 1;

    __shared__ float As[128][36];
    __shared__ float Ws[128][36];

    const int t  = threadIdx.x;
    const int tr = t >> 4;
    const int tc = t & 15;
    const int brow = blockIdx.x * 128;
    const int bcol = blockIdx.y * 128;

    const int srow = t >> 3;
    const int sc4  = (t & 7) << 2;

    const float* Arow0 = A + (size_t)(brow + srow) * K + sc4;
    const float* Arow1 = A + (size_t)(brow + srow + 64) * K + sc4;
    const float* Wrow0 = W + (size_t)(bcol + srow) * K + sc4;
    const float* Wrow1 = W + (size_t)(bcol + srow + 64) * K + sc4;

    float acc00 = 0.f, acc01 = 0.f, acc02 = 0.f, acc03 = 0.f;
    float acc04 = 0.f, acc05 = 0.f, acc06 = 0.f, acc07 = 0.f;
    float acc10 = 0.f, acc11 = 0.f, acc12 = 0.f, acc13 = 0.f;
    float acc14 = 0.f, acc15 = 0.f, acc16 = 0.f, acc17 = 0.f;
    float acc20 = 0.f, acc21 = 0.f, acc22 = 0.f, acc23 = 0.f;
    float acc24 = 0.f, acc25 = 0.f, acc26 = 0.f, acc27 = 0.f;
    float acc30 = 0.f, acc31 = 0.f, acc32 = 0.f, acc33 = 0.f;
    float acc34 = 0.f, acc35 = 0.f, acc36 = 0.f, acc37 = 0.f;

    vf4 aprf0 = *(const vf4*)(Arow0);
    vf4 aprf1 = *(const vf4*)(Arow1);
    vf4 wprf0 = *(const vf4*)(Wrow0);
    vf4 wprf1 = *(const vf4*)(Wrow1);

    for (int k0 = 0; k0 < K; k0 += 32) {
        __syncthreads();
        *(vf4*)(&As[srow     ][sc4]) = aprf0;
        *(vf4*)(&As[srow + 64][sc4]) = aprf1;
        *(vf4*)(&Ws[srow     ][sc4]) = wprf0;
        *(vf4*)(&Ws[srow + 64][sc4]) = wprf1;
        __syncthreads();

        if (k0 + 32 < K) {
            aprf0 = *(const vf4*)(Arow0 + k0 + 32);
            aprf1 = *(const vf4*)(Arow1 + k0 + 32);
            wprf0 = *(const vf4*)(Wrow0 + k0 + 32);
            wprf1 = *(const vf4*)(Wrow1 + k0 + 32);
        }

        #pragma unroll
        for (int kk = 0; kk < 32; kk += 4) {
            const vf4 a0 = *(const vf4*)(&As[tr     ][kk]);
            const vf4 a1 = *(const vf4*)(&As[tr + 32][kk]);
            const vf4 a2 = *(const vf4*)(&As[tr + 64][kk]);
            const vf4 a3 = *(const vf4*)(&As[tr + 96][kk]);
            const vf4 b0 = *(const vf4*)(&Ws[tc      ][kk]);
            const vf4 b1 = *(const vf4*)(&Ws[tc + 16 ][kk]);
            const vf4 b2 = *(const vf4*)(&Ws[tc + 32 ][kk]);
            const vf4 b3 = *(const vf4*)(&Ws[tc + 48 ][kk]);
            const vf4 b4 = *(const vf4*)(&Ws[tc + 64 ][kk]);
            const vf4 b5 = *(const vf4*)(&Ws[tc + 80 ][kk]);
            const vf4 b6 = *(const vf4*)(&Ws[tc + 96 ][kk]);
            const vf4 b7 = *(const vf4*)(&Ws[tc + 112][kk]);
            DOTROW(0, a0);
            DOTROW(1, a1);
            DOTROW(2, a2);
            DOTROW(3, a3);
        }
    }

    if (do_rope) {
        const float pos0 = (float)tokpos[(brow + tr     ) & (SEQ - 1)];
        const float pos1 = (float)tokpos[(brow + tr + 32) & (SEQ - 1)];
        const float pos2 = (float)tokpos[(brow + tr + 64) & (SEQ - 1)];
        const float pos3 = (float)tokpos[(brow + tr + 96) & (SEQ - 1)];
        const bool odd = (tc & 1);
        ROPEJ(0) ROPEJ(1) ROPEJ(2) ROPEJ(3)
        ROPEJ(4) ROPEJ(5) ROPEJ(6) ROPEJ(7)
    }

    CWRITE(0) CWRITE(1) CWRITE(2) CWRITE(3)
}

// ---------------------------------------------------------------------------
// Causal flash attention, fp32, RESTRUCTURED for K/V reuse + occupancy:
// block = (b, h, 128-row q-chunk), 512 threads (8 waves), K/V tiles of 64.
// K/V traffic halves vs 64-row tiles; 2 blocks/CU (LDS 69.6KB of 160KB).
// Thread map: tr = t>>4 (q-rows tr+32i, i=0..3), tc = t&15.
//   QK: s[i][j] over kv-cols tc+16j (rows live in 16 consecutive lanes ->
//       shfl_xor softmax). PV: o[i][d] for dims 4tc..4tc+3.
// P (128x64) doesn't fit the K-reuse buffer -> PV in two 64-row halves.
// Next K/V tile prefetched into registers under the compute phase.
// Fully scalarized (no indexable locals anywhere).
// ---------------------------------------------------------------------------

#define AQK_ROW(I) { \
    const vf4 a = *(const vf4*)(&Qs[tr + 32 * (I)][kk]); \
    s##I##0 = fmaf(a.x, b0.x, fmaf(a.y, b0.y, fmaf(a.z, b0.z, fmaf(a.w, b0.w, s##I##0)))); \
    s##I##1 = fmaf(a.x, b1.x, fmaf(a.y, b1.y, fmaf(a.z, b1.z, fmaf(a.w, b1.w, s##I##1)))); \
    s##I##2 = fmaf(a.x, b2.x, fmaf(a.y, b2.y, fmaf(a.z, b2.z, fmaf(a.w, b2.w, s##I##2)))); \
    s##I##3 = fmaf(a.x, b3.x, fmaf(a.y, b3.y, fmaf(a.z, b3.z, fmaf(a.w, b3.w, s##I##3)))); }

#define AMASK_ROW(I) { \
    const int r = tr + 32 * (I); \
    if (tc      + off > r) s##I##0 = -INFINITY; \
    if (tc + 16 + off > r) s##I##1 = -INFINITY; \
    if (tc + 32 + off > r) s##I##2 = -INFINITY; \
    if (tc + 48 + off > r) s##I##3 = -INFINITY; }

#define ASM_ROW(I) { \
    float mx = fmaxf(fmaxf(s##I##0, s##I##1), fmaxf(s##I##2, s##I##3)); \
    mx = fmaxf(mx, __shfl_xor(mx, 1)); \
    mx = fmaxf(mx, __shfl_xor(mx, 2)); \
    mx = fmaxf(mx, __shfl_xor(mx, 4)); \
    mx = fmaxf(mx, __shfl_xor(mx, 8)); \
    const float mn   = fmaxf(m##I, mx); \
    const float corr = __expf(m##I - mn); \
    m##I = mn; \
    s##I##0 = __expf(s##I##0 - mn); \
    s##I##1 = __expf(s##I##1 - mn); \
    s##I##2 = __expf(s##I##2 - mn); \
    s##I##3 = __expf(s##I##3 - mn); \
    float rs = (s##I##0 + s##I##1) + (s##I##2 + s##I##3); \
    rs += __shfl_xor(rs, 1); \
    rs += __shfl_xor(rs, 2); \
    rs += __shfl_xor(rs, 4); \
    rs += __shfl_xor(rs, 8); \
    l##I = fmaf(l##I, corr, rs); \
    o##I##0 *= corr; o##I##1 *= corr; o##I##2 *= corr; o##I##3 *= corr; }

// store P rows for half: local P row RLOC in [0,64)
#define APST(I, RLOC) { \
    float* pr = &Ks[RLOC][tc]; \
    pr[0]  = s##I##0; pr[16] = s##I##1; pr[32] = s##I##2; pr[48] = s##I##3; }

#define APV_ACC(I, PROW) { \
    const vf4 p = *(const vf4*)(&Ks[PROW][cc]); \
    o##I##0 = fmaf(p.x, v0.x, fmaf(p.y, v1.x, fmaf(p.z, v2.x, fmaf(p.w, v3.x, o##I##0)))); \
    o##I##1 = fmaf(p.x, v0.y, fmaf(p.y, v1.y, fmaf(p.z, v2.y, fmaf(p.w, v3.y, o##I##1)))); \
    o##I##2 = fmaf(p.x, v0.z, fmaf(p.y, v1.z, fmaf(p.z, v2.z, fmaf(p.w, v3.z, o##I##2)))); \
    o##I##3 = fmaf(p.x, v0.w, fmaf(p.y, v1.w, fmaf(p.z, v2.w, fmaf(p.w, v3.w, o##I##3)))); }

#define AOUT(I) { \
    const float invl = 1.0f / l##I; \
    vf4 ov; \
    ov.x = o##I##0 * invl; ov.y = o##I##1 * invl; \
    ov.z = o##I##2 * invl; ov.w = o##I##3 * invl; \
    *(vf4*)(o + base + (size_t)(qc * 128 + tr + 32 * (I)) * DM + (tc << 2)) = ov; }

__global__ __launch_bounds__(512, 2) void attn_kernel(
    const float* __restrict__ q, const float* __restrict__ k,
    const float* __restrict__ v, float* __restrict__ o)
{
    __shared__ float Qs[128][68];   // 34,816 B
    __shared__ float Ks[64][68];    // 17,408 B  (K operand, then P-half)
    __shared__ float Vs[64][68];    // 17,408 B  -> total 69,632 B (<=160KB/WG)

    const int bh = blockIdx.y;
    const int b  = bh >> 4;
    const int h  = bh & (NH - 1);
    const int qc = (int)gridDim.x - 1 - (int)blockIdx.x;   // heavy chunks first

    const int t  = threadIdx.x;
    const int tr = t >> 4;          // 0..31
    const int tc = t & 15;          // 0..15
    const int sc4 = tc << 2;        // 0..60

    const size_t base = (size_t)b * SEQ * DM + (size_t)h * DKH;

    // ---- stage Q chunk (128 rows), scale by 1/sqrt(64) ----
    {
        const float* qp = q + base + (size_t)(qc * 128) * DM;
        vf4 q0 = *(const vf4*)(qp + (size_t)(tr      ) * DM + sc4);
        vf4 q1 = *(const vf4*)(qp + (size_t)(tr + 32 ) * DM + sc4);
        vf4 q2 = *(const vf4*)(qp + (size_t)(tr + 64 ) * DM + sc4);
        vf4 q3 = *(const vf4*)(qp + (size_t)(tr + 96 ) * DM + sc4);
        *(vf4*)(&Qs[tr      ][sc4]) = q0 * 0.125f;
        *(vf4*)(&Qs[tr + 32 ][sc4]) = q1 * 0.125f;
        *(vf4*)(&Qs[tr + 64 ][sc4]) = q2 * 0.125f;
        *(vf4*)(&Qs[tr + 96 ][sc4]) = q3 * 0.125f;
    }

    // prologue: prefetch kv-tile 0 into registers
    const float* kbase = k + base;
    const float* vbase = v + base;
    vf4 kpr0 = *(const vf4*)(kbase + (size_t)(tr     ) * DM + sc4);
    vf4 kpr1 = *(const vf4*)(kbase + (size_t)(tr + 32) * DM + sc4);
    vf4 vpr0 = *(const vf4*)(vbase + (size_t)(tr     ) * DM + sc4);
    vf4 vpr1 = *(const vf4*)(vbase + (size_t)(tr + 32) * DM + sc4);

    float o00 = 0.f, o01 = 0.f, o02 = 0.f, o03 = 0.f;
    float o10 = 0.f, o11 = 0.f, o12 = 0.f, o13 = 0.f;
    float o20 = 0.f, o21 = 0.f, o22 = 0.f, o23 = 0.f;
    float o30 = 0.f, o31 = 0.f, o32 = 0.f, o33 = 0.f;
    float m0 = -INFINITY, m1 = -INFINITY, m2 = -INFINITY, m3 = -INFINITY;
    float l0 = 0.f, l1 = 0.f, l2 = 0.f, l3 = 0.f;

    const int ktmax = 2 * qc + 1;   // kv tiles 0..ktmax

    for (int kt = 0; kt <= ktmax; ++kt) {
        __syncthreads();                    // (A) prev PV done with Ks/Vs; Q staged
        *(vf4*)(&Ks[tr     ][sc4]) = kpr0;
        *(vf4*)(&Ks[tr + 32][sc4]) = kpr1;
        *(vf4*)(&Vs[tr     ][sc4]) = vpr0;
        *(vf4*)(&Vs[tr + 32][sc4]) = vpr1;
        __syncthreads();                    // (B) K/V (and Q, first iter) visible

        if (kt < ktmax) {                   // prefetch next tile under compute
            const float* kp = kbase + (size_t)((kt + 1) * 64) * DM;
            const float* vp = vbase + (size_t)((kt + 1) * 64) * DM;
            kpr0 = *(const vf4*)(kp + (size_t)(tr     ) * DM + sc4);
            kpr1 = *(const vf4*)(kp + (size_t)(tr + 32) * DM + sc4);
            vpr0 = *(const vf4*)(vp + (size_t)(tr     ) * DM + sc4);
            vpr1 = *(const vf4*)(vp + (size_t)(tr + 32) * DM + sc4);
        }

        // ---- S = (Q/8) K^T ----
        float s00 = 0.f, s01 = 0.f, s02 = 0.f, s03 = 0.f;
        float s10 = 0.f, s11 = 0.f, s12 = 0.f, s13 = 0.f;
        float s20 = 0.f, s21 = 0.f, s22 = 0.f, s23 = 0.f;
        float s30 = 0.f, s31 = 0.f, s32 = 0.f, s33 = 0.f;

        #pragma unroll 4
        for (int kk = 0; kk < 64; kk += 4) {
            const vf4 b0 = *(const vf4*)(&Ks[tc     ][kk]);
            const vf4 b1 = *(const vf4*)(&Ks[tc + 16][kk]);
            const vf4 b2 = *(const vf4*)(&Ks[tc + 32][kk]);
            const vf4 b3 = *(const vf4*)(&Ks[tc + 48][kk]);
            AQK_ROW(0) AQK_ROW(1) AQK_ROW(2) AQK_ROW(3)
        }

        if (kt >= 2 * qc) {                 // diagonal region: causal mask
            const int off = (kt - 2 * qc) * 64;
            AMASK_ROW(0) AMASK_ROW(1) AMASK_ROW(2) AMASK_ROW(3)
        }

        // ---- online softmax ----
        ASM_ROW(0) ASM_ROW(1) ASM_ROW(2) ASM_ROW(3)

        // ---- PV in two 64-row halves (P reuses Ks) ----
        __syncthreads();                    // (C) QK reads of Ks done
        APST(0, tr) APST(1, tr + 32)        // P rows 0..63  (q-rows 0..63)
        __syncthreads();                    // (D) P half0 visible
        #pragma unroll 4
        for (int cc = 0; cc < 64; cc += 4) {
            const vf4 v0 = *(const vf4*)(&Vs[cc    ][sc4]);
            const vf4 v1 = *(const vf4*)(&Vs[cc + 1][sc4]);
            const vf4 v2 = *(const vf4*)(&Vs[cc + 2][sc4]);
            const vf4 v3 = *(const vf4*)(&Vs[cc + 3][sc4]);
            APV_ACC(0, tr) APV_ACC(1, tr + 32)
        }
        __syncthreads();                    // (E) PV half0 reads done
        APST(2, tr) APST(3, tr + 32)        // P rows 0..63 (q-rows 64..127)
        __syncthreads();                    // (F) P half1 visible
        #pragma unroll 4
        for (int cc = 0; cc < 64; cc += 4) {
            const vf4 v0 = *(const vf4*)(&Vs[cc    ][sc4]);
            const vf4 v1 = *(const vf4*)(&Vs[cc + 1][sc4]);
            const vf4 v2 = *(const vf4*)(&Vs[cc + 2][sc4]);
            const vf4 v3 = *(const vf4*)(&Vs[cc + 3][sc4]);
            APV_ACC(2, tr) APV_ACC(3, tr + 32)
        }
    }

    AOUT(0) AOUT(1) AOUT(2) AOUT(3)
}

// ---------------------------------------------------------------------------
extern "C" void kernel_launch(void* const* d_in, const int* in_sizes, int n_in,
                              void* d_out, int out_size, void* d_ws, size_t ws_size,
                              hipStream_t stream)
{
    const float* x  = (const float*)d_in[0];
    const int*   tp = (const int*)d_in[1];
    const float* Wq = (const float*)d_in[2];
    const float* Wk = (const float*)d_in[3];
    const float* Wv = (const float*)d_in[4];
    const float* Wo = (const float*)d_in[5];
    float* out = (float*)d_out;

    const size_t NELEM = (size_t)2 * SEQ * DM;   // 16 MB per buffer
    float* qb = (float*)d_ws;
    float* kb = qb + NELEM;
    float* vb = kb + NELEM;
    float* ob = vb + NELEM;

    const int M = 2 * SEQ;                       // 4096 rows

    proj_kernel<<<dim3(M / 128, DM / 128, 3), dim3(512), 0, stream>>>(
        x, Wq, Wk, Wv, qb, kb, vb, tp, M, DM, DM, 0x3);

    // 16 q-chunks of 128 rows x 32 (b,h) pairs
    attn_kernel<<<dim3(SEQ / 128, 2 * NH), dim3(512), 0, stream>>>(qb, kb, vb, ob);

    proj_kernel<<<dim3(M / 128, DM / 128, 1), dim3(512), 0, stream>>>(
        ob, Wo, Wo, Wo, out, out, out, tp, M, DM, DM, 0x0);
}

// Round 7
// 947.500 us; speedup vs baseline: 15.2362x; 1.2435x over previous
//
#include <hip/hip_runtime.h>
#include <math.h>

typedef float vf4 __attribute__((ext_vector_type(4)));

#define SEQ   2048
#define DM    1024
#define NH    16
#define DKH   64
// log2(10000)
#define LOG2_THETA 13.287712379549449f
#define INV_2PI    0.15915494309189535f

// ---------------------------------------------------------------------------
// Projection GEMM (unchanged from round 4 — spill-free, ~510us total)
// ---------------------------------------------------------------------------

#define DOT1(I, J, AV, BV) \
    acc##I##J = fmaf(AV.x, BV.x, fmaf(AV.y, BV.y, fmaf(AV.z, BV.z, fmaf(AV.w, BV.w, acc##I##J))))

#define DOTROW(I, AV) \
    DOT1(I, 0, AV, b0); DOT1(I, 1, AV, b1); DOT1(I, 2, AV, b2); DOT1(I, 3, AV, b3); \
    DOT1(I, 4, AV, b4); DOT1(I, 5, AV, b5); DOT1(I, 6, AV, b6); DOT1(I, 7, AV, b7)

#define ROPE1(I, J, INV) { \
    float rev = pos##I * (INV) * INV_2PI; \
    rev -= floorf(rev); \
    const float sv = __builtin_amdgcn_sinf(rev); \
    const float cv = __builtin_amdgcn_cosf(rev); \
    const float self  = acc##I##J; \
    const float other = __shfl_xor(self, 1); \
    acc##I##J = odd ? fmaf(other, sv, self * cv) : fmaf(-other, sv, self * cv); }

#define ROPEJ(J) { \
    const float fj  = (float)(((tc + 16 * (J)) & 63) >> 1); \
    const float inv = exp2f(fj * (-LOG2_THETA / 32.0f)); \
    ROPE1(0, J, inv) ROPE1(1, J, inv) ROPE1(2, J, inv) ROPE1(3, J, inv) }

#define CWRITE(I) { \
    float* crow = C + (size_t)(brow + tr + 32 * (I)) * N + bcol + tc; \
    crow[0]   = acc##I##0; crow[16]  = acc##I##1; crow[32]  = acc##I##2; crow[48]  = acc##I##3; \
    crow[64]  = acc##I##4; crow[80]  = acc##I##5; crow[96]  = acc##I##6; crow[112] = acc##I##7; }

__global__ __launch_bounds__(512, 2) void proj_kernel(
    const float* __restrict__ A,
    const float* __restrict__ W0, const float* __restrict__ W1, const float* __restrict__ W2,
    float* __restrict__ C0, float* __restrict__ C1, float* __restrict__ C2,
    const int* __restrict__ tokpos,
    int M, int N, int K, int ropeMask)
{
    const int z = blockIdx.z;
    const float* __restrict__ W = (z == 0) ? W0 : ((z == 1) ? W1 : W2);
    float* __restrict__ C       = (z == 0) ? C0 : ((z == 1) ? C1 : C2);
    const bool do_rope = (ropeMask >> z) & 1;

    __shared__ float As[128][36];
    __shared__ float Ws[128][36];

    const int t  = threadIdx.x;
    const int tr = t >> 4;
    const int tc = t & 15;
    const int brow = blockIdx.x * 128;
    const int bcol = blockIdx.y * 128;

    const int srow = t >> 3;
    const int sc4  = (t & 7) << 2;

    const float* Arow0 = A + (size_t)(brow + srow) * K + sc4;
    const float* Arow1 = A + (size_t)(brow + srow + 64) * K + sc4;
    const float* Wrow0 = W + (size_t)(bcol + srow) * K + sc4;
    const float* Wrow1 = W + (size_t)(bcol + srow + 64) * K + sc4;

    float acc00 = 0.f, acc01 = 0.f, acc02 = 0.f, acc03 = 0.f;
    float acc04 = 0.f, acc05 = 0.f, acc06 = 0.f, acc07 = 0.f;
    float acc10 = 0.f, acc11 = 0.f, acc12 = 0.f, acc13 = 0.f;
    float acc14 = 0.f, acc15 = 0.f, acc16 = 0.f, acc17 = 0.f;
    float acc20 = 0.f, acc21 = 0.f, acc22 = 0.f, acc23 = 0.f;
    float acc24 = 0.f, acc25 = 0.f, acc26 = 0.f, acc27 = 0.f;
    float acc30 = 0.f, acc31 = 0.f, acc32 = 0.f, acc33 = 0.f;
    float acc34 = 0.f, acc35 = 0.f, acc36 = 0.f, acc37 = 0.f;

    vf4 aprf0 = *(const vf4*)(Arow0);
    vf4 aprf1 = *(const vf4*)(Arow1);
    vf4 wprf0 = *(const vf4*)(Wrow0);
    vf4 wprf1 = *(const vf4*)(Wrow1);

    for (int k0 = 0; k0 < K; k0 += 32) {
        __syncthreads();
        *(vf4*)(&As[srow     ][sc4]) = aprf0;
        *(vf4*)(&As[srow + 64][sc4]) = aprf1;
        *(vf4*)(&Ws[srow     ][sc4]) = wprf0;
        *(vf4*)(&Ws[srow + 64][sc4]) = wprf1;
        __syncthreads();

        if (k0 + 32 < K) {
            aprf0 = *(const vf4*)(Arow0 + k0 + 32);
            aprf1 = *(const vf4*)(Arow1 + k0 + 32);
            wprf0 = *(const vf4*)(Wrow0 + k0 + 32);
            wprf1 = *(const vf4*)(Wrow1 + k0 + 32);
        }

        #pragma unroll
        for (int kk = 0; kk < 32; kk += 4) {
            const vf4 a0 = *(const vf4*)(&As[tr     ][kk]);
            const vf4 a1 = *(const vf4*)(&As[tr + 32][kk]);
            const vf4 a2 = *(const vf4*)(&As[tr + 64][kk]);
            const vf4 a3 = *(const vf4*)(&As[tr + 96][kk]);
            const vf4 b0 = *(const vf4*)(&Ws[tc      ][kk]);
            const vf4 b1 = *(const vf4*)(&Ws[tc + 16 ][kk]);
            const vf4 b2 = *(const vf4*)(&Ws[tc + 32 ][kk]);
            const vf4 b3 = *(const vf4*)(&Ws[tc + 48 ][kk]);
            const vf4 b4 = *(const vf4*)(&Ws[tc + 64 ][kk]);
            const vf4 b5 = *(const vf4*)(&Ws[tc + 80 ][kk]);
            const vf4 b6 = *(const vf4*)(&Ws[tc + 96 ][kk]);
            const vf4 b7 = *(const vf4*)(&Ws[tc + 112][kk]);
            DOTROW(0, a0);
            DOTROW(1, a1);
            DOTROW(2, a2);
            DOTROW(3, a3);
        }
    }

    if (do_rope) {
        const float pos0 = (float)tokpos[(brow + tr     ) & (SEQ - 1)];
        const float pos1 = (float)tokpos[(brow + tr + 32) & (SEQ - 1)];
        const float pos2 = (float)tokpos[(brow + tr + 64) & (SEQ - 1)];
        const float pos3 = (float)tokpos[(brow + tr + 96) & (SEQ - 1)];
        const bool odd = (tc & 1);
        ROPEJ(0) ROPEJ(1) ROPEJ(2) ROPEJ(3)
        ROPEJ(4) ROPEJ(5) ROPEJ(6) ROPEJ(7)
    }

    CWRITE(0) CWRITE(1) CWRITE(2) CWRITE(3)
}

// ---------------------------------------------------------------------------
// Causal flash attention, fp32, BALANCED PAIRING:
// one block = (b, h, q-tile pair {p, 31-p}), two sequential 64-row phases.
// Every block does exactly (p+1) + (32-p) = 33 kv-tile-iterations -> zero
// load imbalance (round 5: 12% time-avg occupancy from 2..32-iter spread).
// Grid 512 equal blocks of 256 threads; LDS 52KB -> 2 blocks/CU co-resident
// for the whole kernel (flat 8 waves/CU, barrier overlap between blocks).
// P (64x64) fits the Ks buffer whole -> 4 barriers/iter.
// Register prefetch of next K/V tile, carried across the phase boundary.
// Fully scalarized (no indexable locals).
// ---------------------------------------------------------------------------

#define QK_ROW(I) { \
    const vf4 a = *(const vf4*)(&Qs[tr + 16 * (I)][kk]); \
    s##I##0 = fmaf(a.x, b0.x, fmaf(a.y, b0.y, fmaf(a.z, b0.z, fmaf(a.w, b0.w, s##I##0)))); \
    s##I##1 = fmaf(a.x, b1.x, fmaf(a.y, b1.y, fmaf(a.z, b1.z, fmaf(a.w, b1.w, s##I##1)))); \
    s##I##2 = fmaf(a.x, b2.x, fmaf(a.y, b2.y, fmaf(a.z, b2.z, fmaf(a.w, b2.w, s##I##2)))); \
    s##I##3 = fmaf(a.x, b3.x, fmaf(a.y, b3.y, fmaf(a.z, b3.z, fmaf(a.w, b3.w, s##I##3)))); }

#define MASK_ROW(I) { \
    if (tc      > tr + 16 * (I)) s##I##0 = -INFINITY; \
    if (tc + 16 > tr + 16 * (I)) s##I##1 = -INFINITY; \
    if (tc + 32 > tr + 16 * (I)) s##I##2 = -INFINITY; \
    if (tc + 48 > tr + 16 * (I)) s##I##3 = -INFINITY; }

#define SOFTMAX_ROW(I) { \
    float mx = fmaxf(fmaxf(s##I##0, s##I##1), fmaxf(s##I##2, s##I##3)); \
    mx = fmaxf(mx, __shfl_xor(mx, 1)); \
    mx = fmaxf(mx, __shfl_xor(mx, 2)); \
    mx = fmaxf(mx, __shfl_xor(mx, 4)); \
    mx = fmaxf(mx, __shfl_xor(mx, 8)); \
    const float mn   = fmaxf(m##I, mx); \
    const float corr = __expf(m##I - mn); \
    m##I = mn; \
    s##I##0 = __expf(s##I##0 - mn); \
    s##I##1 = __expf(s##I##1 - mn); \
    s##I##2 = __expf(s##I##2 - mn); \
    s##I##3 = __expf(s##I##3 - mn); \
    float rs = (s##I##0 + s##I##1) + (s##I##2 + s##I##3); \
    rs += __shfl_xor(rs, 1); \
    rs += __shfl_xor(rs, 2); \
    rs += __shfl_xor(rs, 4); \
    rs += __shfl_xor(rs, 8); \
    l##I = fmaf(l##I, corr, rs); \
    o##I##0 *= corr; o##I##1 *= corr; o##I##2 *= corr; o##I##3 *= corr; }

#define PSTORE_ROW(I) { \
    float* pr = &Ks[tr + 16 * (I)][tc]; \
    pr[0]  = s##I##0; pr[16] = s##I##1; pr[32] = s##I##2; pr[48] = s##I##3; }

#define PV_ROW(I) { \
    const vf4 p4 = *(const vf4*)(&Ks[tr + 16 * (I)][cc]); \
    o##I##0 = fmaf(p4.x, v0.x, fmaf(p4.y, v1.x, fmaf(p4.z, v2.x, fmaf(p4.w, v3.x, o##I##0)))); \
    o##I##1 = fmaf(p4.x, v0.y, fmaf(p4.y, v1.y, fmaf(p4.z, v2.y, fmaf(p4.w, v3.y, o##I##1)))); \
    o##I##2 = fmaf(p4.x, v0.z, fmaf(p4.y, v1.z, fmaf(p4.z, v2.z, fmaf(p4.w, v3.z, o##I##2)))); \
    o##I##3 = fmaf(p4.x, v0.w, fmaf(p4.y, v1.w, fmaf(p4.z, v2.w, fmaf(p4.w, v3.w, o##I##3)))); }

#define OUT_ROW(I) { \
    const float invl = 1.0f / l##I; \
    vf4 ov; \
    ov.x = o##I##0 * invl; ov.y = o##I##1 * invl; \
    ov.z = o##I##2 * invl; ov.w = o##I##3 * invl; \
    *(vf4*)(o + base + (size_t)(qi * 64 + tr + 16 * (I)) * DM + (tc << 2)) = ov; }

#define KV_PREFETCH(PTRK, PTRV) { \
    kpr0 = *(const vf4*)((PTRK) + (size_t)(lrow     ) * DM + lc4); \
    kpr1 = *(const vf4*)((PTRK) + (size_t)(lrow + 16) * DM + lc4); \
    kpr2 = *(const vf4*)((PTRK) + (size_t)(lrow + 32) * DM + lc4); \
    kpr3 = *(const vf4*)((PTRK) + (size_t)(lrow + 48) * DM + lc4); \
    vpr0 = *(const vf4*)((PTRV) + (size_t)(lrow     ) * DM + lc4); \
    vpr1 = *(const vf4*)((PTRV) + (size_t)(lrow + 16) * DM + lc4); \
    vpr2 = *(const vf4*)((PTRV) + (size_t)(lrow + 32) * DM + lc4); \
    vpr3 = *(const vf4*)((PTRV) + (size_t)(lrow + 48) * DM + lc4); }

__global__ __launch_bounds__(256, 2) void attn_kernel(
    const float* __restrict__ q, const float* __restrict__ k,
    const float* __restrict__ v, float* __restrict__ o)
{
    __shared__ float Qs[64][68];
    __shared__ float Ks[64][68];   // K operand, then P
    __shared__ float Vs[64][68];

    const int bh = blockIdx.y;
    const int b  = bh >> 4;
    const int h  = bh & (NH - 1);
    const int p  = blockIdx.x;       // pair index 0..15 -> q-tiles {p, 31-p}

    const int t  = threadIdx.x;
    const int tr = t >> 4;
    const int tc = t & 15;

    const size_t base = (size_t)b * SEQ * DM + (size_t)h * DKH;
    const float* kbase = k + base;
    const float* vbase = v + base;

    const int lrow = t >> 4;          // 0..15
    const int lc4  = (t & 15) << 2;   // 0..60

    // prologue: prefetch kv tile 0 (used by phase 0)
    vf4 kpr0, kpr1, kpr2, kpr3, vpr0, vpr1, vpr2, vpr3;
    KV_PREFETCH(kbase, vbase)

    #pragma unroll 1
    for (int ph = 0; ph < 2; ++ph) {
        const int qi = ph ? (SEQ / 64 - 1 - p) : p;   // phase q-tile

        // ---- stage Q tile (visibility: barriers A+B of first iter) ----
        {
            const float* qp = q + base + (size_t)(qi * 64) * DM;
            vf4 q0 = *(const vf4*)(qp + (size_t)(lrow     ) * DM + lc4);
            vf4 q1 = *(const vf4*)(qp + (size_t)(lrow + 16) * DM + lc4);
            vf4 q2 = *(const vf4*)(qp + (size_t)(lrow + 32) * DM + lc4);
            vf4 q3 = *(const vf4*)(qp + (size_t)(lrow + 48) * DM + lc4);
            *(vf4*)(&Qs[lrow     ][lc4]) = q0 * 0.125f;   // 1/sqrt(64)
            *(vf4*)(&Qs[lrow + 16][lc4]) = q1 * 0.125f;
            *(vf4*)(&Qs[lrow + 32][lc4]) = q2 * 0.125f;
            *(vf4*)(&Qs[lrow + 48][lc4]) = q3 * 0.125f;
        }

        float o00 = 0.f, o01 = 0.f, o02 = 0.f, o03 = 0.f;
        float o10 = 0.f, o11 = 0.f, o12 = 0.f, o13 = 0.f;
        float o20 = 0.f, o21 = 0.f, o22 = 0.f, o23 = 0.f;
        float o30 = 0.f, o31 = 0.f, o32 = 0.f, o33 = 0.f;
        float m0 = -INFINITY, m1 = -INFINITY, m2 = -INFINITY, m3 = -INFINITY;
        float l0 = 0.f, l1 = 0.f, l2 = 0.f, l3 = 0.f;

        #pragma unroll 1
        for (int kt = 0; kt <= qi; ++kt) {
            __syncthreads();                 // (A) prev PV done / Q staged everywhere
            *(vf4*)(&Ks[lrow     ][lc4]) = kpr0;
            *(vf4*)(&Ks[lrow + 16][lc4]) = kpr1;
            *(vf4*)(&Ks[lrow + 32][lc4]) = kpr2;
            *(vf4*)(&Ks[lrow + 48][lc4]) = kpr3;
            *(vf4*)(&Vs[lrow     ][lc4]) = vpr0;
            *(vf4*)(&Vs[lrow + 16][lc4]) = vpr1;
            *(vf4*)(&Vs[lrow + 32][lc4]) = vpr2;
            *(vf4*)(&Vs[lrow + 48][lc4]) = vpr3;
            __syncthreads();                 // (B) K/V (+Q on first iter) visible

            // prefetch next kv tile (within phase, or phase-1 tile 0)
            if (kt < qi) {
                const float* kp = kbase + (size_t)((kt + 1) * 64) * DM;
                const float* vp = vbase + (size_t)((kt + 1) * 64) * DM;
                KV_PREFETCH(kp, vp)
            } else if (ph == 0) {
                KV_PREFETCH(kbase, vbase)    // phase 1 starts at kv tile 0
            }

            // ---- S = (Q/8) K^T ----
            float s00 = 0.f, s01 = 0.f, s02 = 0.f, s03 = 0.f;
            float s10 = 0.f, s11 = 0.f, s12 = 0.f, s13 = 0.f;
            float s20 = 0.f, s21 = 0.f, s22 = 0.f, s23 = 0.f;
            float s30 = 0.f, s31 = 0.f, s32 = 0.f, s33 = 0.f;

            #pragma unroll 4
            for (int kk = 0; kk < 64; kk += 4) {
                const vf4 b0 = *(const vf4*)(&Ks[tc     ][kk]);
                const vf4 b1 = *(const vf4*)(&Ks[tc + 16][kk]);
                const vf4 b2 = *(const vf4*)(&Ks[tc + 32][kk]);
                const vf4 b3 = *(const vf4*)(&Ks[tc + 48][kk]);
                QK_ROW(0) QK_ROW(1) QK_ROW(2) QK_ROW(3)
            }

            if (kt == qi) {       // diagonal tile: causal mask
                MASK_ROW(0) MASK_ROW(1) MASK_ROW(2) MASK_ROW(3)
            }

            // ---- online softmax (row in 16 consecutive lanes) ----
            SOFTMAX_ROW(0) SOFTMAX_ROW(1) SOFTMAX_ROW(2) SOFTMAX_ROW(3)

            __syncthreads();                 // (C) QK reads of Ks done
            PSTORE_ROW(0) PSTORE_ROW(1) PSTORE_ROW(2) PSTORE_ROW(3)
            __syncthreads();                 // (D) P visible

            // ---- O += P V ----
            #pragma unroll 4
            for (int cc = 0; cc < 64; cc += 4) {
                const vf4 v0 = *(const vf4*)(&Vs[cc    ][tc << 2]);
                const vf4 v1 = *(const vf4*)(&Vs[cc + 1][tc << 2]);
                const vf4 v2 = *(const vf4*)(&Vs[cc + 2][tc << 2]);
                const vf4 v3 = *(const vf4*)(&Vs[cc + 3][tc << 2]);
                PV_ROW(0) PV_ROW(1) PV_ROW(2) PV_ROW(3)
            }
        }

        OUT_ROW(0) OUT_ROW(1) OUT_ROW(2) OUT_ROW(3)
    }
}

// ---------------------------------------------------------------------------
extern "C" void kernel_launch(void* const* d_in, const int* in_sizes, int n_in,
                              void* d_out, int out_size, void* d_ws, size_t ws_size,
                              hipStream_t stream)
{
    const float* x  = (const float*)d_in[0];
    const int*   tp = (const int*)d_in[1];
    const float* Wq = (const float*)d_in[2];
    const float* Wk = (const float*)d_in[3];
    const float* Wv = (const float*)d_in[4];
    const float* Wo = (const float*)d_in[5];
    float* out = (float*)d_out;

    const size_t NELEM = (size_t)2 * SEQ * DM;   // 16 MB per buffer
    float* qb = (float*)d_ws;
    float* kb = qb + NELEM;
    float* vb = kb + NELEM;
    float* ob = vb + NELEM;

    const int M = 2 * SEQ;                       // 4096 rows

    proj_kernel<<<dim3(M / 128, DM / 128, 3), dim3(512), 0, stream>>>(
        x, Wq, Wk, Wv, qb, kb, vb, tp, M, DM, DM, 0x3);

    // 16 balanced q-tile pairs x 32 (b,h): every block = exactly 33 kv-iters
    attn_kernel<<<dim3(SEQ / 128, 2 * NH), dim3(256), 0, stream>>>(qb, kb, vb, ob);

    proj_kernel<<<dim3(M / 128, DM / 128, 1), dim3(512), 0, stream>>>(
        ob, Wo, Wo, Wo, out, out, out, tp, M, DM, DM, 0x0);
}

// Round 8
// 520.249 us; speedup vs baseline: 27.7489x; 1.8212x over previous
//
#include <hip/hip_runtime.h>
#include <math.h>

typedef float vf4 __attribute__((ext_vector_type(4)));
typedef _Float16 f16x8 __attribute__((ext_vector_type(8)));
typedef float f32x4 __attribute__((ext_vector_type(4)));

#define SEQ   2048
#define DM    1024
#define NH    16
#define DKH   64
// log2(10000)
#define LOG2_THETA 13.287712379549449f
#define INV_2PI    0.15915494309189535f

#define MFMA16(A, B, C) __builtin_amdgcn_mfma_f32_16x16x32_f16(A, B, C, 0, 0, 0)

// ---------------------------------------------------------------------------
// Pack fp32 row-major [R][1024] -> fp16 MFMA-tiled [R/16][128][16][8].
// Fragment load then becomes: lane l reads 16B at tile_base + l*16 (coalesced).
// Reads are fully coalesced (consecutive threads walk kb), writes are 16B at
// 256B stride (acceptable: total pack traffic ~56MB).
// ---------------------------------------------------------------------------
__device__ __forceinline__ void pack_chunk(const float* __restrict__ s,
                                           _Float16* __restrict__ d, int c)
{
    const int row = c >> 7;          // source row
    const int kb  = c & 127;         // 8-wide k block
    const float* sp = s + ((size_t)row << 10) + (kb << 3);
    const vf4 f0 = *(const vf4*)(sp);
    const vf4 f1 = *(const vf4*)(sp + 4);
    f16x8 h;
    h[0] = (_Float16)f0.x; h[1] = (_Float16)f0.y; h[2] = (_Float16)f0.z; h[3] = (_Float16)f0.w;
    h[4] = (_Float16)f1.x; h[5] = (_Float16)f1.y; h[6] = (_Float16)f1.z; h[7] = (_Float16)f1.w;
    const size_t tc = (((size_t)(row >> 4)) << 11) + ((size_t)kb << 4) + (row & 15);
    *(f16x8*)(d + tc * 8) = h;
}

__global__ __launch_bounds__(256) void pack5_kernel(
    const float* __restrict__ x,
    const float* __restrict__ wq, const float* __restrict__ wk,
    const float* __restrict__ wv, const float* __restrict__ wo,
    _Float16* __restrict__ xh, _Float16* __restrict__ wqh,
    _Float16* __restrict__ wkh, _Float16* __restrict__ wvh, _Float16* __restrict__ woh)
{
    const int bid = blockIdx.x;
    const float* s; _Float16* d; int base;
    if (bid < 2048) {                 // x: 4096 rows -> 524288 chunks
        s = x; d = xh; base = bid << 8;
    } else {                          // W's: 1024 rows -> 131072 chunks each
        const int t   = bid - 2048;
        const int sel = t >> 9;
        base = (t & 511) << 8;
        s = (sel == 0) ? wq  : (sel == 1) ? wk  : (sel == 2) ? wv  : wo;
        d = (sel == 0) ? wqh : (sel == 1) ? wkh : (sel == 2) ? wvh : woh;
    }
    pack_chunk(s, d, base + (int)threadIdx.x);
}

__global__ __launch_bounds__(256) void pack1_kernel(
    const float* __restrict__ s, _Float16* __restrict__ d)
{
    pack_chunk(s, d, ((int)blockIdx.x << 8) + (int)threadIdx.x);
}

// ---------------------------------------------------------------------------
// MFMA projection: C[m,n] = sum_k A[m,k] * W[n,k], fp16 in / fp32 out.
// A,W pre-packed tiled fp16 (layout above). No LDS, no barriers: fragments
// load straight from global (weights L2-resident, x via L3).
// 256 threads = 4 waves (2x2); wave tile 64x64 = 4x4 mfma_f32_16x16x32_f16
// fragments; K-loop unrolled x2 with named ping-pong register sets so the
// next step's 8 loads issue under the current 16 MFMAs (no indexable locals).
// A-frag: lane l = row l&15, k = (l>>4)*8+i. C/D (m89): col=l&15,
// row=(l>>4)*4+reg. RoPE fused in fp32 epilogue (pair partner = lane^1).
// ---------------------------------------------------------------------------

#define LDSET(P, KS) \
    P##a0 = *(const f16x8*)(pA0 + (KS) * 512); \
    P##a1 = *(const f16x8*)(pA1 + (KS) * 512); \
    P##a2 = *(const f16x8*)(pA2 + (KS) * 512); \
    P##a3 = *(const f16x8*)(pA3 + (KS) * 512); \
    P##b0 = *(const f16x8*)(pB0 + (KS) * 512); \
    P##b1 = *(const f16x8*)(pB1 + (KS) * 512); \
    P##b2 = *(const f16x8*)(pB2 + (KS) * 512); \
    P##b3 = *(const f16x8*)(pB3 + (KS) * 512);

#define MMSET(P) \
    c00 = MFMA16(P##a0, P##b0, c00); c01 = MFMA16(P##a0, P##b1, c01); \
    c02 = MFMA16(P##a0, P##b2, c02); c03 = MFMA16(P##a0, P##b3, c03); \
    c10 = MFMA16(P##a1, P##b0, c10); c11 = MFMA16(P##a1, P##b1, c11); \
    c12 = MFMA16(P##a1, P##b2, c12); c13 = MFMA16(P##a1, P##b3, c13); \
    c20 = MFMA16(P##a2, P##b0, c20); c21 = MFMA16(P##a2, P##b1, c21); \
    c22 = MFMA16(P##a2, P##b2, c22); c23 = MFMA16(P##a2, P##b3, c23); \
    c30 = MFMA16(P##a3, P##b0, c30); c31 = MFMA16(P##a3, P##b1, c31); \
    c32 = MFMA16(P##a3, P##b2, c32); c33 = MFMA16(P##a3, P##b3, c33);

#define ROPE_REG(I, J, JJ) { \
    const int row = (mbase + (I)) * 16 + ((l >> 4) << 2) + (JJ); \
    const float pos = (float)tokpos[row & (SEQ - 1)]; \
    float rev = pos * inv; \
    rev -= floorf(rev); \
    const float sv = __builtin_amdgcn_sinf(rev); \
    const float cv = __builtin_amdgcn_cosf(rev); \
    const float self  = c##I##J[JJ]; \
    const float other = __shfl_xor(self, 1); \
    c##I##J[JJ] = (l & 1) ? fmaf(other, sv, self * cv) : fmaf(-other, sv, self * cv); }

#define STORE_FRAG(I, J) { \
    const int col = (nbase + (J)) * 16 + (l & 15); \
    float* cp = C + (size_t)((mbase + (I)) * 16 + ((l >> 4) << 2)) * DM + col; \
    if (do_rope) { \
        const float fj  = (float)((col & 63) >> 1); \
        const float inv = exp2f(fj * (-LOG2_THETA / 32.0f)) * INV_2PI; \
        ROPE_REG(I, J, 0) ROPE_REG(I, J, 1) ROPE_REG(I, J, 2) ROPE_REG(I, J, 3) \
    } \
    cp[0]        = c##I##J[0]; \
    cp[DM]       = c##I##J[1]; \
    cp[2 * DM]   = c##I##J[2]; \
    cp[3 * DM]   = c##I##J[3]; }

__global__ __launch_bounds__(256) void mfma_proj_kernel(
    const _Float16* __restrict__ Ah,
    const _Float16* __restrict__ Wh0, const _Float16* __restrict__ Wh1,
    const _Float16* __restrict__ Wh2,
    float* __restrict__ C0, float* __restrict__ C1, float* __restrict__ C2,
    const int* __restrict__ tokpos, int ropeMask)
{
    const int z = blockIdx.z;
    const _Float16* __restrict__ Wh = (z == 0) ? Wh0 : ((z == 1) ? Wh1 : Wh2);
    float* __restrict__ C           = (z == 0) ? C0  : ((z == 1) ? C1  : C2);
    const bool do_rope = (ropeMask >> z) & 1;

    const int l = threadIdx.x & 63;
    const int w = threadIdx.x >> 6;
    const int mbase = blockIdx.x * 8 + (w >> 1) * 4;   // 16-row block index
    const int nbase = blockIdx.y * 8 + (w & 1) * 4;    // 16-col block index

    // per-lane fragment pointers; one rb = 128 kb-tiles * 128 elems = 16384
    const _Float16* pA0 = Ah + (size_t)(mbase    ) * 16384 + l * 8;
    const _Float16* pA1 = Ah + (size_t)(mbase + 1) * 16384 + l * 8;
    const _Float16* pA2 = Ah + (size_t)(mbase + 2) * 16384 + l * 8;
    const _Float16* pA3 = Ah + (size_t)(mbase + 3) * 16384 + l * 8;
    const _Float16* pB0 = Wh + (size_t)(nbase    ) * 16384 + l * 8;
    const _Float16* pB1 = Wh + (size_t)(nbase + 1) * 16384 + l * 8;
    const _Float16* pB2 = Wh + (size_t)(nbase + 2) * 16384 + l * 8;
    const _Float16* pB3 = Wh + (size_t)(nbase + 3) * 16384 + l * 8;

    f32x4 c00 = {0.f, 0.f, 0.f, 0.f}, c01 = {0.f, 0.f, 0.f, 0.f};
    f32x4 c02 = {0.f, 0.f, 0.f, 0.f}, c03 = {0.f, 0.f, 0.f, 0.f};
    f32x4 c10 = {0.f, 0.f, 0.f, 0.f}, c11 = {0.f, 0.f, 0.f, 0.f};
    f32x4 c12 = {0.f, 0.f, 0.f, 0.f}, c13 = {0.f, 0.f, 0.f, 0.f};
    f32x4 c20 = {0.f, 0.f, 0.f, 0.f}, c21 = {0.f, 0.f, 0.f, 0.f};
    f32x4 c22 = {0.f, 0.f, 0.f, 0.f}, c23 = {0.f, 0.f, 0.f, 0.f};
    f32x4 c30 = {0.f, 0.f, 0.f, 0.f}, c31 = {0.f, 0.f, 0.f, 0.f};
    f32x4 c32 = {0.f, 0.f, 0.f, 0.f}, c33 = {0.f, 0.f, 0.f, 0.f};

    f16x8 xa0, xa1, xa2, xa3, xb0, xb1, xb2, xb3;
    f16x8 ya0, ya1, ya2, ya3, yb0, yb1, yb2, yb3;

    LDSET(x, 0)
    #pragma unroll 1
    for (int ks = 0; ks < 32; ks += 2) {
        LDSET(y, ks + 1)                     // issue next-step loads early
        MMSET(x)
        if (ks + 2 < 32) { LDSET(x, ks + 2) }
        MMSET(y)
    }

    STORE_FRAG(0, 0) STORE_FRAG(0, 1) STORE_FRAG(0, 2) STORE_FRAG(0, 3)
    STORE_FRAG(1, 0) STORE_FRAG(1, 1) STORE_FRAG(1, 2) STORE_FRAG(1, 3)
    STORE_FRAG(2, 0) STORE_FRAG(2, 1) STORE_FRAG(2, 2) STORE_FRAG(2, 3)
    STORE_FRAG(3, 0) STORE_FRAG(3, 1) STORE_FRAG(3, 2) STORE_FRAG(3, 3)
}

// ---------------------------------------------------------------------------
// Causal flash attention, fp32 — UNCHANGED from round 7 (balanced pairing:
// block = (b,h,q-tile pair {p,31-p}), 33 kv-iters per block, 2 blocks/CU).
// ---------------------------------------------------------------------------

#define QK_ROW(I) { \
    const vf4 a = *(const vf4*)(&Qs[tr + 16 * (I)][kk]); \
    s##I##0 = fmaf(a.x, b0.x, fmaf(a.y, b0.y, fmaf(a.z, b0.z, fmaf(a.w, b0.w, s##I##0)))); \
    s##I##1 = fmaf(a.x, b1.x, fmaf(a.y, b1.y, fmaf(a.z, b1.z, fmaf(a.w, b1.w, s##I##1)))); \
    s##I##2 = fmaf(a.x, b2.x, fmaf(a.y, b2.y, fmaf(a.z, b2.z, fmaf(a.w, b2.w, s##I##2)))); \
    s##I##3 = fmaf(a.x, b3.x, fmaf(a.y, b3.y, fmaf(a.z, b3.z, fmaf(a.w, b3.w, s##I##3)))); }

#define MASK_ROW(I) { \
    if (tc      > tr + 16 * (I)) s##I##0 = -INFINITY; \
    if (tc + 16 > tr + 16 * (I)) s##I##1 = -INFINITY; \
    if (tc + 32 > tr + 16 * (I)) s##I##2 = -INFINITY; \
    if (tc + 48 > tr + 16 * (I)) s##I##3 = -INFINITY; }

#define SOFTMAX_ROW(I) { \
    float mx = fmaxf(fmaxf(s##I##0, s##I##1), fmaxf(s##I##2, s##I##3)); \
    mx = fmaxf(mx, __shfl_xor(mx, 1)); \
    mx = fmaxf(mx, __shfl_xor(mx, 2)); \
    mx = fmaxf(mx, __shfl_xor(mx, 4)); \
    mx = fmaxf(mx, __shfl_xor(mx, 8)); \
    const float mn   = fmaxf(m##I, mx); \
    const float corr = __expf(m##I - mn); \
    m##I = mn; \
    s##I##0 = __expf(s##I##0 - mn); \
    s##I##1 = __expf(s##I##1 - mn); \
    s##I##2 = __expf(s##I##2 - mn); \
    s##I##3 = __expf(s##I##3 - mn); \
    float rs = (s##I##0 + s##I##1) + (s##I##2 + s##I##3); \
    rs += __shfl_xor(rs, 1); \
    rs += __shfl_xor(rs, 2); \
    rs += __shfl_xor(rs, 4); \
    rs += __shfl_xor(rs, 8); \
    l##I = fmaf(l##I, corr, rs); \
    o##I##0 *= corr; o##I##1 *= corr; o##I##2 *= corr; o##I##3 *= corr; }

#define PSTORE_ROW(I) { \
    float* pr = &Ks[tr + 16 * (I)][tc]; \
    pr[0]  = s##I##0; pr[16] = s##I##1; pr[32] = s##I##2; pr[48] = s##I##3; }

#define PV_ROW(I) { \
    const vf4 p4 = *(const vf4*)(&Ks[tr + 16 * (I)][cc]); \
    o##I##0 = fmaf(p4.x, v0.x, fmaf(p4.y, v1.x, fmaf(p4.z, v2.x, fmaf(p4.w, v3.x, o##I##0)))); \
    o##I##1 = fmaf(p4.x, v0.y, fmaf(p4.y, v1.y, fmaf(p4.z, v2.y, fmaf(p4.w, v3.y, o##I##1)))); \
    o##I##2 = fmaf(p4.x, v0.z, fmaf(p4.y, v1.z, fmaf(p4.z, v2.z, fmaf(p4.w, v3.z, o##I##2)))); \
    o##I##3 = fmaf(p4.x, v0.w, fmaf(p4.y, v1.w, fmaf(p4.z, v2.w, fmaf(p4.w, v3.w, o##I##3)))); }

#define OUT_ROW(I) { \
    const float invl = 1.0f / l##I; \
    vf4 ov; \
    ov.x = o##I##0 * invl; ov.y = o##I##1 * invl; \
    ov.z = o##I##2 * invl; ov.w = o##I##3 * invl; \
    *(vf4*)(o + base + (size_t)(qi * 64 + tr + 16 * (I)) * DM + (tc << 2)) = ov; }

#define KV_PREFETCH(PTRK, PTRV) { \
    kpr0 = *(const vf4*)((PTRK) + (size_t)(lrow     ) * DM + lc4); \
    kpr1 = *(const vf4*)((PTRK) + (size_t)(lrow + 16) * DM + lc4); \
    kpr2 = *(const vf4*)((PTRK) + (size_t)(lrow + 32) * DM + lc4); \
    kpr3 = *(const vf4*)((PTRK) + (size_t)(lrow + 48) * DM + lc4); \
    vpr0 = *(const vf4*)((PTRV) + (size_t)(lrow     ) * DM + lc4); \
    vpr1 = *(const vf4*)((PTRV) + (size_t)(lrow + 16) * DM + lc4); \
    vpr2 = *(const vf4*)((PTRV) + (size_t)(lrow + 32) * DM + lc4); \
    vpr3 = *(const vf4*)((PTRV) + (size_t)(lrow + 48) * DM + lc4); }

__global__ __launch_bounds__(256, 2) void attn_kernel(
    const float* __restrict__ q, const float* __restrict__ k,
    const float* __restrict__ v, float* __restrict__ o)
{
    __shared__ float Qs[64][68];
    __shared__ float Ks[64][68];   // K operand, then P
    __shared__ float Vs[64][68];

    const int bh = blockIdx.y;
    const int b  = bh >> 4;
    const int h  = bh & (NH - 1);
    const int p  = blockIdx.x;       // pair index 0..15 -> q-tiles {p, 31-p}

    const int t  = threadIdx.x;
    const int tr = t >> 4;
    const int tc = t & 15;

    const size_t base = (size_t)b * SEQ * DM + (size_t)h * DKH;
    const float* kbase = k + base;
    const float* vbase = v + base;

    const int lrow = t >> 4;          // 0..15
    const int lc4  = (t & 15) << 2;   // 0..60

    vf4 kpr0, kpr1, kpr2, kpr3, vpr0, vpr1, vpr2, vpr3;
    KV_PREFETCH(kbase, vbase)

    #pragma unroll 1
    for (int ph = 0; ph < 2; ++ph) {
        const int qi = ph ? (SEQ / 64 - 1 - p) : p;

        {
            const float* qp = q + base + (size_t)(qi * 64) * DM;
            vf4 q0 = *(const vf4*)(qp + (size_t)(lrow     ) * DM + lc4);
            vf4 q1 = *(const vf4*)(qp + (size_t)(lrow + 16) * DM + lc4);
            vf4 q2 = *(const vf4*)(qp + (size_t)(lrow + 32) * DM + lc4);
            vf4 q3 = *(const vf4*)(qp + (size_t)(lrow + 48) * DM + lc4);
            *(vf4*)(&Qs[lrow     ][lc4]) = q0 * 0.125f;
            *(vf4*)(&Qs[lrow + 16][lc4]) = q1 * 0.125f;
            *(vf4*)(&Qs[lrow + 32][lc4]) = q2 * 0.125f;
            *(vf4*)(&Qs[lrow + 48][lc4]) = q3 * 0.125f;
        }

        float o00 = 0.f, o01 = 0.f, o02 = 0.f, o03 = 0.f;
        float o10 = 0.f, o11 = 0.f, o12 = 0.f, o13 = 0.f;
        float o20 = 0.f, o21 = 0.f, o22 = 0.f, o23 = 0.f;
        float o30 = 0.f, o31 = 0.f, o32 = 0.f, o33 = 0.f;
        float m0 = -INFINITY, m1 = -INFINITY, m2 = -INFINITY, m3 = -INFINITY;
        float l0 = 0.f, l1 = 0.f, l2 = 0.f, l3 = 0.f;

        #pragma unroll 1
        for (int kt = 0; kt <= qi; ++kt) {
            __syncthreads();                 // (A) prev PV done / Q staged
            *(vf4*)(&Ks[lrow     ][lc4]) = kpr0;
            *(vf4*)(&Ks[lrow + 16][lc4]) = kpr1;
            *(vf4*)(&Ks[lrow + 32][lc4]) = kpr2;
            *(vf4*)(&Ks[lrow + 48][lc4]) = kpr3;
            *(vf4*)(&Vs[lrow     ][lc4]) = vpr0;
            *(vf4*)(&Vs[lrow + 16][lc4]) = vpr1;
            *(vf4*)(&Vs[lrow + 32][lc4]) = vpr2;
            *(vf4*)(&Vs[lrow + 48][lc4]) = vpr3;
            __syncthreads();                 // (B) K/V visible

            if (kt < qi) {
                const float* kp = kbase + (size_t)((kt + 1) * 64) * DM;
                const float* vp = vbase + (size_t)((kt + 1) * 64) * DM;
                KV_PREFETCH(kp, vp)
            } else if (ph == 0) {
                KV_PREFETCH(kbase, vbase)    // phase 1 restarts at kv tile 0
            }

            float s00 = 0.f, s01 = 0.f, s02 = 0.f, s03 = 0.f;
            float s10 = 0.f, s11 = 0.f, s12 = 0.f, s13 = 0.f;
            float s20 = 0.f, s21 = 0.f, s22 = 0.f, s23 = 0.f;
            float s30 = 0.f, s31 = 0.f, s32 = 0.f, s33 = 0.f;

            #pragma unroll 4
            for (int kk = 0; kk < 64; kk += 4) {
                const vf4 b0 = *(const vf4*)(&Ks[tc     ][kk]);
                const vf4 b1 = *(const vf4*)(&Ks[tc + 16][kk]);
                const vf4 b2 = *(const vf4*)(&Ks[tc + 32][kk]);
                const vf4 b3 = *(const vf4*)(&Ks[tc + 48][kk]);
                QK_ROW(0) QK_ROW(1) QK_ROW(2) QK_ROW(3)
            }

            if (kt == qi) {
                MASK_ROW(0) MASK_ROW(1) MASK_ROW(2) MASK_ROW(3)
            }

            SOFTMAX_ROW(0) SOFTMAX_ROW(1) SOFTMAX_ROW(2) SOFTMAX_ROW(3)

            __syncthreads();                 // (C) QK reads of Ks done
            PSTORE_ROW(0) PSTORE_ROW(1) PSTORE_ROW(2) PSTORE_ROW(3)
            __syncthreads();                 // (D) P visible

            #pragma unroll 4
            for (int cc = 0; cc < 64; cc += 4) {
                const vf4 v0 = *(const vf4*)(&Vs[cc    ][tc << 2]);
                const vf4 v1 = *(const vf4*)(&Vs[cc + 1][tc << 2]);
                const vf4 v2 = *(const vf4*)(&Vs[cc + 2][tc << 2]);
                const vf4 v3 = *(const vf4*)(&Vs[cc + 3][tc << 2]);
                PV_ROW(0) PV_ROW(1) PV_ROW(2) PV_ROW(3)
            }
        }

        OUT_ROW(0) OUT_ROW(1) OUT_ROW(2) OUT_ROW(3)
    }
}

// ---------------------------------------------------------------------------
extern "C" void kernel_launch(void* const* d_in, const int* in_sizes, int n_in,
                              void* d_out, int out_size, void* d_ws, size_t ws_size,
                              hipStream_t stream)
{
    const float* x  = (const float*)d_in[0];
    const int*   tp = (const int*)d_in[1];
    const float* Wq = (const float*)d_in[2];
    const float* Wk = (const float*)d_in[3];
    const float* Wv = (const float*)d_in[4];
    const float* Wo = (const float*)d_in[5];
    float* out = (float*)d_out;

    // ws layout (80 MB):
    //  [ 0..16) qb   [16..32) kb   [32..48) vb   [48..64) ob      (fp32)
    //  [64..72) xh (fp16 tiled; reused as obh after attention)
    //  [72..74) wqh  [74..76) wkh  [76..78) wvh  [78..80) woh     (fp16 tiled)
    char* wsb = (char*)d_ws;
    float* qb = (float*)(wsb);
    float* kb = (float*)(wsb + ((size_t)16 << 20));
    float* vb = (float*)(wsb + ((size_t)32 << 20));
    float* ob = (float*)(wsb + ((size_t)48 << 20));
    _Float16* xh  = (_Float16*)(wsb + ((size_t)64 << 20));
    _Float16* wqh = (_Float16*)(wsb + ((size_t)72 << 20));
    _Float16* wkh = (_Float16*)(wsb + ((size_t)74 << 20));
    _Float16* wvh = (_Float16*)(wsb + ((size_t)76 << 20));
    _Float16* woh = (_Float16*)(wsb + ((size_t)78 << 20));
    _Float16* obh = xh;   // xh dead after qkv projections

    // 1) pack x + all four weights to fp16 tiled
    pack5_kernel<<<dim3(4096), dim3(256), 0, stream>>>(
        x, Wq, Wk, Wv, Wo, xh, wqh, wkh, wvh, woh);

    // 2) fused Q/K/V projections on matrix cores (RoPE on z=0,1)
    mfma_proj_kernel<<<dim3(32, 8, 3), dim3(256), 0, stream>>>(
        xh, wqh, wkh, wvh, qb, kb, vb, tp, 0x3);

    // 3) causal flash attention (fp32, unchanged)
    attn_kernel<<<dim3(SEQ / 128, 2 * NH), dim3(256), 0, stream>>>(qb, kb, vb, ob);

    // 4) pack attention output to fp16 tiled
    pack1_kernel<<<dim3(2048), dim3(256), 0, stream>>>(ob, obh);

    // 5) output projection on matrix cores
    mfma_proj_kernel<<<dim3(32, 8, 1), dim3(256), 0, stream>>>(
        obh, woh, woh, woh, out, out, out, tp, 0x0);
}

// Round 9
// 214.807 us; speedup vs baseline: 67.2059x; 2.4219x over previous
//
#include <hip/hip_runtime.h>
#include <math.h>

typedef float vf4 __attribute__((ext_vector_type(4)));
typedef _Float16 f16x8 __attribute__((ext_vector_type(8)));
typedef float f32x4 __attribute__((ext_vector_type(4)));

#define SEQ   2048
#define DM    1024
#define NH    16
#define DKH   64
// log2(10000)
#define LOG2_THETA 13.287712379549449f
#define INV_2PI    0.15915494309189535f

#define MFMA16(A, B, C) __builtin_amdgcn_mfma_f32_16x16x32_f16(A, B, C, 0, 0, 0)

// ---------------------------------------------------------------------------
// Tiled fp16 layout "PT": [row>>4][col>>3][row&15][col&7]
//   f16 offset = ((rb*128 + kb)*16 + r)*8 + kk     (for D=1024 => 128 kb)
// A/B fragment for mfma_f32_16x16x32_f16 (validated round 8): lane l holds
//   row/col = l&15, k = (l>>4)*8 + i  -> one coalesced 16B load per lane.
// C/D layout (validated): col = l&15, row = (l>>4)*4 + reg.
// "VT" (per b,h; for PV B-operand): [dh>>4][s>>3][dh&15][s&7], 131072 f16.
// ---------------------------------------------------------------------------

// ---------------------------------------------------------------------------
// pack: fp32 row-major [R][1024] -> fp16 PT
// ---------------------------------------------------------------------------
__device__ __forceinline__ void pack_chunk(const float* __restrict__ s,
                                           _Float16* __restrict__ d, int c)
{
    const int row = c >> 7;
    const int kb  = c & 127;
    const float* sp = s + ((size_t)row << 10) + (kb << 3);
    const vf4 f0 = *(const vf4*)(sp);
    const vf4 f1 = *(const vf4*)(sp + 4);
    f16x8 hv;
    hv[0] = (_Float16)f0.x; hv[1] = (_Float16)f0.y; hv[2] = (_Float16)f0.z; hv[3] = (_Float16)f0.w;
    hv[4] = (_Float16)f1.x; hv[5] = (_Float16)f1.y; hv[6] = (_Float16)f1.z; hv[7] = (_Float16)f1.w;
    const size_t tc = (((size_t)(row >> 4)) << 11) + ((size_t)kb << 4) + (row & 15);
    *(f16x8*)(d + tc * 8) = hv;
}

__global__ __launch_bounds__(256) void pack5_kernel(
    const float* __restrict__ x,
    const float* __restrict__ wq, const float* __restrict__ wk,
    const float* __restrict__ wv, const float* __restrict__ wo,
    _Float16* __restrict__ xh, _Float16* __restrict__ wqh,
    _Float16* __restrict__ wkh, _Float16* __restrict__ wvh, _Float16* __restrict__ woh)
{
    const int bid = blockIdx.x;
    const float* s; _Float16* d; int base;
    if (bid < 2048) {
        s = x; d = xh; base = bid << 8;
    } else {
        const int t   = bid - 2048;
        const int sel = t >> 9;
        base = (t & 511) << 8;
        s = (sel == 0) ? wq  : (sel == 1) ? wk  : (sel == 2) ? wv  : wo;
        d = (sel == 0) ? wqh : (sel == 1) ? wkh : (sel == 2) ? wvh : woh;
    }
    pack_chunk(s, d, base + (int)threadIdx.x);
}

// ---------------------------------------------------------------------------
// MFMA projection with mode-dispatched epilogue:
//   omode==1          : fp32 row-major store (o-proj)
//   omode==0 && z==0  : RoPE + *0.125 -> fp16 PT   (q)
//   omode==0 && z==1  : RoPE          -> fp16 PT   (k)
//   omode==0 && z==2  :                fp16 VT     (v)
// ---------------------------------------------------------------------------

#define LDSET(P, KS) \
    P##a0 = *(const f16x8*)(pA0 + (KS) * 512); \
    P##a1 = *(const f16x8*)(pA1 + (KS) * 512); \
    P##a2 = *(const f16x8*)(pA2 + (KS) * 512); \
    P##a3 = *(const f16x8*)(pA3 + (KS) * 512); \
    P##b0 = *(const f16x8*)(pB0 + (KS) * 512); \
    P##b1 = *(const f16x8*)(pB1 + (KS) * 512); \
    P##b2 = *(const f16x8*)(pB2 + (KS) * 512); \
    P##b3 = *(const f16x8*)(pB3 + (KS) * 512);

#define MMSET(P) \
    c00 = MFMA16(P##a0, P##b0, c00); c01 = MFMA16(P##a0, P##b1, c01); \
    c02 = MFMA16(P##a0, P##b2, c02); c03 = MFMA16(P##a0, P##b3, c03); \
    c10 = MFMA16(P##a1, P##b0, c10); c11 = MFMA16(P##a1, P##b1, c11); \
    c12 = MFMA16(P##a1, P##b2, c12); c13 = MFMA16(P##a1, P##b3, c13); \
    c20 = MFMA16(P##a2, P##b0, c20); c21 = MFMA16(P##a2, P##b1, c21); \
    c22 = MFMA16(P##a2, P##b2, c22); c23 = MFMA16(P##a2, P##b3, c23); \
    c30 = MFMA16(P##a3, P##b0, c30); c31 = MFMA16(P##a3, P##b1, c31); \
    c32 = MFMA16(P##a3, P##b2, c32); c33 = MFMA16(P##a3, P##b3, c33);

#define ROPE_REG(I, J, JJ) { \
    const int row = (mbase + (I)) * 16 + ((l >> 4) << 2) + (JJ); \
    const float pos = (float)tokpos[row & (SEQ - 1)]; \
    float rev = pos * inv; \
    rev -= floorf(rev); \
    const float sv = __builtin_amdgcn_sinf(rev); \
    const float cv = __builtin_amdgcn_cosf(rev); \
    const float self  = c##I##J[JJ]; \
    const float other = __shfl_xor(self, 1); \
    c##I##J[JJ] = (l & 1) ? fmaf(other, sv, self * cv) : fmaf(-other, sv, self * cv); }

#define EPI_PT(I, J) { \
    const int col = (nbase + (J)) * 16 + (l & 15); \
    { const float inv = exp2f(((float)((col & 63) >> 1)) * (-LOG2_THETA / 32.0f)) * INV_2PI; \
      ROPE_REG(I, J, 0) ROPE_REG(I, J, 1) ROPE_REG(I, J, 2) ROPE_REG(I, J, 3) } \
    const int rowb = (mbase + (I)) * 16 + ((l >> 4) << 2); \
    const size_t bidx = ((size_t)((rowb >> 4) * 128 + (col >> 3)) * 16 + (rowb & 15)) * 8 + (col & 7); \
    outPT[bidx]      = (_Float16)(c##I##J[0] * sc); \
    outPT[bidx + 8]  = (_Float16)(c##I##J[1] * sc); \
    outPT[bidx + 16] = (_Float16)(c##I##J[2] * sc); \
    outPT[bidx + 24] = (_Float16)(c##I##J[3] * sc); }

#define EPI_VT(I, J) { \
    const int col = (nbase + (J)) * 16 + (l & 15); \
    const int hh = col >> 6; const int dh = col & 63; \
    const int rowb = (mbase + (I)) * 16 + ((l >> 4) << 2); \
    const int bb = rowb >> 11; const int ss = rowb & 2047; \
    _Float16* vbp = Ovt + ((size_t)(bb * 16 + hh) << 17); \
    const size_t vidx = ((size_t)((dh >> 4) * 256 + (ss >> 3)) * 16 + (dh & 15)) * 8 + (ss & 7); \
    vbp[vidx]     = (_Float16)c##I##J[0]; \
    vbp[vidx + 1] = (_Float16)c##I##J[1]; \
    vbp[vidx + 2] = (_Float16)c##I##J[2]; \
    vbp[vidx + 3] = (_Float16)c##I##J[3]; }

#define EPI_F32(I, J) { \
    const int col = (nbase + (J)) * 16 + (l & 15); \
    float* cp = Cf + (size_t)((mbase + (I)) * 16 + ((l >> 4) << 2)) * DM + col; \
    cp[0] = c##I##J[0]; cp[DM] = c##I##J[1]; cp[2 * DM] = c##I##J[2]; cp[3 * DM] = c##I##J[3]; }

#define EPI_ALL(M) \
    M(0,0) M(0,1) M(0,2) M(0,3) M(1,0) M(1,1) M(1,2) M(1,3) \
    M(2,0) M(2,1) M(2,2) M(2,3) M(3,0) M(3,1) M(3,2) M(3,3)

__global__ __launch_bounds__(256) void mfma_proj_kernel(
    const _Float16* __restrict__ Ah,
    const _Float16* __restrict__ Wh0, const _Float16* __restrict__ Wh1,
    const _Float16* __restrict__ Wh2,
    _Float16* __restrict__ Oq, _Float16* __restrict__ Ok, _Float16* __restrict__ Ovt,
    float* __restrict__ Cf,
    const int* __restrict__ tokpos, int omode)
{
    const int z = blockIdx.z;
    const _Float16* __restrict__ Wh = (z == 0) ? Wh0 : ((z == 1) ? Wh1 : Wh2);

    const int l = threadIdx.x & 63;
    const int w = threadIdx.x >> 6;
    const int mbase = blockIdx.x * 8 + (w >> 1) * 4;
    const int nbase = blockIdx.y * 8 + (w & 1) * 4;

    const _Float16* pA0 = Ah + (size_t)(mbase    ) * 16384 + l * 8;
    const _Float16* pA1 = Ah + (size_t)(mbase + 1) * 16384 + l * 8;
    const _Float16* pA2 = Ah + (size_t)(mbase + 2) * 16384 + l * 8;
    const _Float16* pA3 = Ah + (size_t)(mbase + 3) * 16384 + l * 8;
    const _Float16* pB0 = Wh + (size_t)(nbase    ) * 16384 + l * 8;
    const _Float16* pB1 = Wh + (size_t)(nbase + 1) * 16384 + l * 8;
    const _Float16* pB2 = Wh + (size_t)(nbase + 2) * 16384 + l * 8;
    const _Float16* pB3 = Wh + (size_t)(nbase + 3) * 16384 + l * 8;

    f32x4 c00 = {0.f,0.f,0.f,0.f}, c01 = {0.f,0.f,0.f,0.f};
    f32x4 c02 = {0.f,0.f,0.f,0.f}, c03 = {0.f,0.f,0.f,0.f};
    f32x4 c10 = {0.f,0.f,0.f,0.f}, c11 = {0.f,0.f,0.f,0.f};
    f32x4 c12 = {0.f,0.f,0.f,0.f}, c13 = {0.f,0.f,0.f,0.f};
    f32x4 c20 = {0.f,0.f,0.f,0.f}, c21 = {0.f,0.f,0.f,0.f};
    f32x4 c22 = {0.f,0.f,0.f,0.f}, c23 = {0.f,0.f,0.f,0.f};
    f32x4 c30 = {0.f,0.f,0.f,0.f}, c31 = {0.f,0.f,0.f,0.f};
    f32x4 c32 = {0.f,0.f,0.f,0.f}, c33 = {0.f,0.f,0.f,0.f};

    f16x8 xa0, xa1, xa2, xa3, xb0, xb1, xb2, xb3;
    f16x8 ya0, ya1, ya2, ya3, yb0, yb1, yb2, yb3;

    LDSET(x, 0)
    #pragma unroll 1
    for (int ks = 0; ks < 32; ks += 2) {
        LDSET(y, ks + 1)
        MMSET(x)
        if (ks + 2 < 32) { LDSET(x, ks + 2) }
        MMSET(y)
    }

    if (omode == 1) {
        EPI_ALL(EPI_F32)
    } else if (z == 0) {
        _Float16* outPT = Oq; const float sc = 0.125f;   // 1/sqrt(64) folded
        EPI_ALL(EPI_PT)
    } else if (z == 1) {
        _Float16* outPT = Ok; const float sc = 1.0f;
        EPI_ALL(EPI_PT)
    } else {
        EPI_ALL(EPI_VT)
    }
}

// ---------------------------------------------------------------------------
// MFMA causal flash attention, fp16 in / fp32 accum, balanced pairing.
// Block = (b,h,pair{p,31-p}), 256 thr = 4 waves; wave owns a 16-row q-strip.
// Q A-frags from global PT (coalesced). K/V staged LDS (layout-preserving).
// S frags: q-row in 16 lanes -> butterfly softmax (same shape as rounds 5-8).
// P -> wave-private LDS [16][72] f16 (no barrier; 8 lanes/quad = free),
// then A-frags for PV. O written as fp16 PT directly (o-proj input).
// 2 barriers/tile. T14 register prefetch of next K/V tile.
// ---------------------------------------------------------------------------

#define AKV_PRF(KT) { \
    kpf0 = *(const f16x8*)(kh  + kbase0 + (size_t)(KT) * 65536); \
    kpf1 = *(const f16x8*)(kh  + kbase1 + (size_t)(KT) * 65536); \
    vpf0 = *(const f16x8*)(vtb + vbase0 + (size_t)(KT) * 1024); \
    vpf1 = *(const f16x8*)(vtb + vbase1 + (size_t)(KT) * 1024); }

#define AQK(JF) \
    const f16x8 kA##JF = *(const f16x8*)(Ksh + (JF) * 1024 + (l >> 4) * 128 + (l & 15) * 8); \
    const f16x8 kB##JF = *(const f16x8*)(Ksh + (JF) * 1024 + (4 + (l >> 4)) * 128 + (l & 15) * 8); \
    f32x4 s##JF = MFMA16(qa0, kA##JF, zf4); \
    s##JF = MFMA16(qa1, kB##JF, s##JF);

#define AMASK(R) { \
    const int qg = wsq + ((l >> 4) << 2) + (R); \
    if ((l & 15)      > qg) s0[R] = -INFINITY; \
    if ((l & 15) + 16 > qg) s1[R] = -INFINITY; \
    if ((l & 15) + 32 > qg) s2[R] = -INFINITY; \
    if ((l & 15) + 48 > qg) s3[R] = -INFINITY; }

#define ASOFT(R) { \
    float mx = fmaxf(fmaxf(s0[R], s1[R]), fmaxf(s2[R], s3[R])); \
    mx = fmaxf(mx, __shfl_xor(mx, 1)); \
    mx = fmaxf(mx, __shfl_xor(mx, 2)); \
    mx = fmaxf(mx, __shfl_xor(mx, 4)); \
    mx = fmaxf(mx, __shfl_xor(mx, 8)); \
    const float mn = fmaxf(m##R, mx); \
    const float corr = __expf(m##R - mn); \
    m##R = mn; \
    s0[R] = __expf(s0[R] - mn); s1[R] = __expf(s1[R] - mn); \
    s2[R] = __expf(s2[R] - mn); s3[R] = __expf(s3[R] - mn); \
    float rs = (s0[R] + s1[R]) + (s2[R] + s3[R]); \
    rs += __shfl_xor(rs, 1); rs += __shfl_xor(rs, 2); \
    rs += __shfl_xor(rs, 4); rs += __shfl_xor(rs, 8); \
    l##R = fmaf(l##R, corr, rs); \
    o0[R] *= corr; o1[R] *= corr; o2[R] *= corr; o3[R] *= corr; }

#define APSTORE(R) { \
    _Float16* pr = pw + (((l >> 4) << 2) + (R)) * 72 + (l & 15); \
    pr[0]  = (_Float16)s0[R]; pr[16] = (_Float16)s1[R]; \
    pr[32] = (_Float16)s2[R]; pr[48] = (_Float16)s3[R]; }

#define APV(FD) { \
    const f16x8 vA = *(const f16x8*)(Vsh + (FD) * 1024 + (l >> 4) * 128 + (l & 15) * 8); \
    const f16x8 vB = *(const f16x8*)(Vsh + (FD) * 1024 + (4 + (l >> 4)) * 128 + (l & 15) * 8); \
    o##FD = MFMA16(pa0, vA, o##FD); \
    o##FD = MFMA16(pa1, vB, o##FD); }

#define AOUTF(FD) { \
    const int kb = h * 8 + (FD) * 2 + ((l & 15) >> 3); \
    const size_t oidx = ((size_t)(rbq * 128 + kb) * 16 + ((l >> 4) << 2)) * 8 + (l & 7); \
    obh[oidx]      = (_Float16)(o##FD[0] * il0); \
    obh[oidx + 8]  = (_Float16)(o##FD[1] * il1); \
    obh[oidx + 16] = (_Float16)(o##FD[2] * il2); \
    obh[oidx + 24] = (_Float16)(o##FD[3] * il3); }

__global__ __launch_bounds__(256, 2) void attn_kernel(
    const _Float16* __restrict__ qh, const _Float16* __restrict__ kh,
    const _Float16* __restrict__ vt, _Float16* __restrict__ obh)
{
    __shared__ _Float16 Ksh[4096];      // 8KB  (K tile, PT-chunk layout)
    __shared__ _Float16 Vsh[4096];      // 8KB  (V tile, VT-chunk layout)
    __shared__ _Float16 Psh[4][1152];   // 9KB  (per-wave P, 16 rows x 72)

    const int bh = blockIdx.y;
    const int b  = bh >> 4;
    const int h  = bh & 15;
    const int p  = blockIdx.x;         // pair {p, 31-p}

    const int t  = threadIdx.x;
    const int ws = t >> 6;
    const int l  = t & 63;
    const int wsq = ws * 16;

    const _Float16* vtb = vt + ((size_t)(b * 16 + h) << 17);
    _Float16* pw = &Psh[ws][0];

    // staging source offsets (unit u0 = t, u1 = t+256)
    const size_t kbase0 = ((size_t)(b * 128 + (t >> 7)) * 128 + 8 * h) * 128 + (size_t)(t & 127) * 8;
    const size_t kbase1 = ((size_t)(b * 128 + (t >> 7) + 2) * 128 + 8 * h) * 128 + (size_t)(t & 127) * 8;
    const size_t vbase0 = (size_t)(t >> 7) * 32768 + (size_t)(t & 127) * 8;
    const size_t vbase1 = (size_t)((t >> 7) + 2) * 32768 + (size_t)(t & 127) * 8;

    const f32x4 zf4 = {0.f, 0.f, 0.f, 0.f};

    f16x8 kpf0, kpf1, vpf0, vpf1;
    AKV_PRF(0)

    #pragma unroll 1
    for (int ph = 0; ph < 2; ++ph) {
        const int qi = ph ? (SEQ / 64 - 1 - p) : p;
        const int rbq = b * 128 + qi * 4 + ws;

        // Q A-frags for this wave's 16-row strip (global, coalesced)
        const size_t qoff = ((size_t)rbq * 128 + 8 * h + (l >> 4)) * 128 + (size_t)(l & 15) * 8;
        const f16x8 qa0 = *(const f16x8*)(qh + qoff);
        const f16x8 qa1 = *(const f16x8*)(qh + qoff + 512);

        f32x4 o0 = zf4, o1 = zf4, o2 = zf4, o3 = zf4;
        float m0 = -INFINITY, m1 = -INFINITY, m2 = -INFINITY, m3 = -INFINITY;
        float l0 = 0.f, l1 = 0.f, l2 = 0.f, l3 = 0.f;

        #pragma unroll 1
        for (int kt = 0; kt <= qi; ++kt) {
            __syncthreads();                         // all waves done with prev tile
            *(f16x8*)(Ksh + t * 8)         = kpf0;
            *(f16x8*)(Ksh + (t + 256) * 8) = kpf1;
            *(f16x8*)(Vsh + t * 8)         = vpf0;
            *(f16x8*)(Vsh + (t + 256) * 8) = vpf1;
            __syncthreads();                         // K/V visible

            if (kt < qi)       { AKV_PRF(kt + 1) }
            else if (ph == 0)  { AKV_PRF(0) }        // phase 1 restarts at tile 0

            // ---- S = Q K^T (Q pre-scaled by 1/8 in projection) ----
            AQK(0) AQK(1) AQK(2) AQK(3)

            if (kt == qi) { AMASK(0) AMASK(1) AMASK(2) AMASK(3) }

            // ---- online softmax (q-row lives in 16 lanes) ----
            ASOFT(0) ASOFT(1) ASOFT(2) ASOFT(3)

            // ---- P -> wave-private LDS (no barrier needed) ----
            APSTORE(0) APSTORE(1) APSTORE(2) APSTORE(3)

            // ---- O += P V ----
            const f16x8 pa0 = *(const f16x8*)(pw + (l & 15) * 72 + ((l >> 4) << 3));
            const f16x8 pa1 = *(const f16x8*)(pw + (l & 15) * 72 + 32 + ((l >> 4) << 3));
            APV(0) APV(1) APV(2) APV(3)
        }

        const float il0 = 1.0f / l0, il1 = 1.0f / l1;
        const float il2 = 1.0f / l2, il3 = 1.0f / l3;
        AOUTF(0) AOUTF(1) AOUTF(2) AOUTF(3)
    }
}

// ---------------------------------------------------------------------------
extern "C" void kernel_launch(void* const* d_in, const int* in_sizes, int n_in,
                              void* d_out, int out_size, void* d_ws, size_t ws_size,
                              hipStream_t stream)
{
    const float* x  = (const float*)d_in[0];
    const int*   tp = (const int*)d_in[1];
    const float* Wq = (const float*)d_in[2];
    const float* Wk = (const float*)d_in[3];
    const float* Wv = (const float*)d_in[4];
    const float* Wo = (const float*)d_in[5];
    float* out = (float*)d_out;

    // ws layout (48 MB, all fp16):
    //  [ 0, 8)  xh      [ 8,10) wqh  [10,12) wkh  [12,14) wvh  [14,16) woh
    //  [16,24)  qh(PT)  [24,32) kh(PT)  [32,40) vt(VT)  [40,48) obh(PT)
    char* wsb = (char*)d_ws;
    _Float16* xh  = (_Float16*)(wsb);
    _Float16* wqh = (_Float16*)(wsb + ((size_t)8  << 20));
    _Float16* wkh = (_Float16*)(wsb + ((size_t)10 << 20));
    _Float16* wvh = (_Float16*)(wsb + ((size_t)12 << 20));
    _Float16* woh = (_Float16*)(wsb + ((size_t)14 << 20));
    _Float16* qh  = (_Float16*)(wsb + ((size_t)16 << 20));
    _Float16* kh  = (_Float16*)(wsb + ((size_t)24 << 20));
    _Float16* vt  = (_Float16*)(wsb + ((size_t)32 << 20));
    _Float16* obh = (_Float16*)(wsb + ((size_t)40 << 20));

    // 1) pack x + weights to fp16 PT
    pack5_kernel<<<dim3(4096), dim3(256), 0, stream>>>(
        x, Wq, Wk, Wv, Wo, xh, wqh, wkh, wvh, woh);

    // 2) Q/K/V projections on matrix cores; epilogue emits attention-ready
    //    fp16 layouts (q: RoPE+scale PT, k: RoPE PT, v: VT)
    mfma_proj_kernel<<<dim3(32, 8, 3), dim3(256), 0, stream>>>(
        xh, wqh, wkh, wvh, qh, kh, vt, (float*)nullptr, tp, 0);

    // 3) MFMA causal flash attention -> obh (fp16 PT, o-proj-ready)
    attn_kernel<<<dim3(SEQ / 128, 2 * NH), dim3(256), 0, stream>>>(qh, kh, vt, obh);

    // 4) output projection on matrix cores -> fp32 out
    mfma_proj_kernel<<<dim3(32, 8, 1), dim3(256), 0, stream>>>(
        obh, woh, woh, woh, (_Float16*)nullptr, (_Float16*)nullptr, (_Float16*)nullptr,
        out, tp, 1);
}